// Round 3
// baseline (7444.795 us; speedup 1.0000x reference)
//
#include <hip/hip_runtime.h>

typedef unsigned int u32;
typedef unsigned short u16;
typedef unsigned long long u64;

using short8 = __attribute__((ext_vector_type(8))) short;
using f32x4  = __attribute__((ext_vector_type(4))) float;

// ---------- bf16 helpers (manual, RTN-even) ----------
__device__ __forceinline__ u32 f2bf(float f) {
    u32 u = __float_as_uint(f);
    return (u + 0x7fffu + ((u >> 16) & 1u)) >> 16;
}
__device__ __forceinline__ u32 pk(float a, float b) {
    return f2bf(a) | (f2bf(b) << 16);
}
__device__ __forceinline__ float bflo(u32 u) { return __uint_as_float(u << 16); }
__device__ __forceinline__ float bfhi(u32 u) { return __uint_as_float(u & 0xffff0000u); }
__device__ __forceinline__ float bfu(u16 u) { return __uint_as_float(((u32)u) << 16); }

union U8 { u32 u[4]; short8 v; };

// 4 edges x 4 cols x 2 k fp32 FMA block from packed operands (GRU kernel)
__device__ __forceinline__ void fma_4e4j(const uint4& mi, const uint4& wq, float (&acc)[4][4]) {
    const u32* mp = (const u32*)&mi;
    const u32* wp = (const u32*)&wq;
    float wl[4], wh[4];
#pragma unroll
    for (int j = 0; j < 4; ++j) { wl[j] = bflo(wp[j]); wh[j] = bfhi(wp[j]); }
#pragma unroll
    for (int e = 0; e < 4; ++e) {
        float ml = bflo(mp[e]), mh = bfhi(mp[e]);
#pragma unroll
        for (int j = 0; j < 4; ++j)
            acc[e][j] = fmaf(mh, wh[j], fmaf(ml, wl[j], acc[e][j]));
    }
}

// ---------- input projection + LayerNorm + ReLU (wave per node) ----------
__global__ void k_input_proj(const float* __restrict__ x, const float* __restrict__ in_w,
                             const float* __restrict__ in_b, const float* __restrict__ ln_g,
                             const float* __restrict__ ln_b, float* __restrict__ h,
                             u16* __restrict__ hbf, int n_nodes) {
    const int lane = threadIdx.x & 63;
    const int node = blockIdx.x * 4 + (threadIdx.x >> 6);
    if (node >= n_nodes) return;
    float acc = in_b[lane];
#pragma unroll
    for (int k = 0; k < 4; ++k) acc = fmaf(x[node * 4 + k], in_w[k * 64 + lane], acc);
    float s = acc;
#pragma unroll
    for (int off = 32; off > 0; off >>= 1) s += __shfl_xor(s, off);
    float mu = s * (1.f / 64.f);
    float d = acc - mu;
    float vs = d * d;
#pragma unroll
    for (int off = 32; off > 0; off >>= 1) vs += __shfl_xor(vs, off);
    float inv = rsqrtf(vs * (1.f / 64.f) + 1e-5f);
    float hv = fmaxf(d * inv * ln_g[lane] + ln_b[lane], 0.f);
    h[(size_t)node * 64 + lane] = hv;
    hbf[(size_t)node * 64 + lane] = (u16)f2bf(hv);
}

// ---------- (type,dst)-sort: histogram, scan, scatter ----------
__global__ void k_hist(const int* __restrict__ dst, const int* __restrict__ ety,
                       int* __restrict__ cnt, int M, int N) {
    int i = blockIdx.x * 256 + threadIdx.x;
    if (i < M) atomicAdd(&cnt[(ety[i] & 1) * N + dst[i]], 1);
}

__global__ void k_scan1(int* __restrict__ data, int* __restrict__ part, int N) {
    __shared__ int s[1024];
    const int t = threadIdx.x;
    const int i = blockIdx.x * 1024 + t;
    int v = (i < N) ? data[i] : 0;
    s[t] = v;
    __syncthreads();
#pragma unroll
    for (int d = 1; d < 1024; d <<= 1) {
        int x = (t >= d) ? s[t - d] : 0;
        __syncthreads();
        s[t] += x;
        __syncthreads();
    }
    if (i < N) data[i] = s[t] - v;  // exclusive
    if (t == 1023) part[blockIdx.x] = s[1023];
}

__global__ void k_scan2(int* __restrict__ part, int nb) {
    if (threadIdx.x == 0 && blockIdx.x == 0) {
        int a = 0;
        for (int i = 0; i < nb; ++i) { int t = part[i]; part[i] = a; a += t; }
    }
}

__global__ void k_scan3(int* __restrict__ data, const int* __restrict__ part, int N) {
    int i = blockIdx.x * 1024 + threadIdx.x;
    if (i < N) data[i] += part[blockIdx.x];
}

__global__ void k_scatter(const int* __restrict__ src, const int* __restrict__ dst,
                          const int* __restrict__ ety, int* __restrict__ cursor,
                          int* __restrict__ srcP, int* __restrict__ dstP, int M, int N) {
    int e = blockIdx.x * 256 + threadIdx.x;
    if (e < M) {
        int d = dst[e];
        int t = ety[e] & 1;
        int pos = atomicAdd(&cursor[t * N + d], 1);
        srcP[pos] = src[e] | (t << 30);
        dstP[pos] = d;
    }
}

// ---------- edge message MLP via MFMA + run-reduced scatter-add ----------
// Edges pre-sorted by (type,dst): tiles are type-uniform except at most one
// boundary m-tile; dst runs contiguous. B-fragments (W1/W2, both types) live in
// registers; A staged in LDS bf16 A-layout; hidden LDS roundtrip; fp32 msg
// roundtrip in the dead A region; run-reduction -> one atomic per (run, col).
__global__ __launch_bounds__(256, 2) void k_edge_mlp(
    const u16* __restrict__ hbf, const int* __restrict__ srcP, const int* __restrict__ dstP,
    const float* __restrict__ w1, const float* __restrict__ b1,
    const float* __restrict__ w2, const float* __restrict__ b2,
    float* __restrict__ agg, int M) {
    __shared__ u32 sU[64 * 69];      // A tile (64 x 68 u32 used) / msg fp32 (69 x 64)
    __shared__ u32 sHid[64 * 36];    // hidden, 64 rows x 72 bf16 (stride 36 u32)
    __shared__ int sDst[64];
    __shared__ int sTy[64];

    const int tid = threadIdx.x;
    const int l = tid & 63;
    const int wv = tid >> 6;
    const int w0 = wv & 1, w1i = wv >> 1;  // m-pair, n-pair
    const int l15 = l & 15, quad = l >> 4;
    const f32x4 vzero = {0.f, 0.f, 0.f, 0.f};

    // ---- persistent B fragments + bias registers (loaded once) ----
    short8 Bf1[2][4][2], Bf2[2][2][2];
    float b1r[2][2], b2r[2][2];
#pragma unroll
    for (int t = 0; t < 2; ++t)
#pragma unroll
        for (int ni = 0; ni < 2; ++ni) {
            const int c = (2 * w1i + ni) * 16 + l15;
            b1r[t][ni] = b1[t * 64 + c];
            b2r[t][ni] = b2[t * 64 + c];
#pragma unroll
            for (int s = 0; s < 4; ++s) {
                U8 tmp;
                const float* wp = w1 + (size_t)t * 8192 + (size_t)(s * 32 + quad * 8) * 64 + c;
#pragma unroll
                for (int jp = 0; jp < 4; ++jp) tmp.u[jp] = pk(wp[(2 * jp) * 64], wp[(2 * jp + 1) * 64]);
                Bf1[t][s][ni] = tmp.v;
            }
#pragma unroll
            for (int s = 0; s < 2; ++s) {
                U8 tmp;
                const float* wp = w2 + (size_t)t * 4096 + (size_t)(s * 32 + quad * 8) * 64 + c;
#pragma unroll
                for (int jp = 0; jp < 4; ++jp) tmp.u[jp] = pk(wp[(2 * jp) * 64], wp[(2 * jp + 1) * 64]);
                Bf2[t][s][ni] = tmp.v;
            }
        }

    const int n_tiles = (M + 63) >> 6;
    for (int tile = blockIdx.x; tile < n_tiles; tile += gridDim.x) {
        const int base = tile << 6;
        __syncthreads();  // prev tile's msg reads / staging reads complete
        if (tid < 64) {   // meta
            int e = base + tid;
            bool ok = e < M;
            int ec = ok ? e : (M - 1);
            u32 sp = (u32)srcP[ec];
            sTy[tid] = ok ? (int)((sp >> 30) & 1u) : 2;
            sDst[tid] = ok ? dstP[ec] : -1;
        }
        {  // stage A: lane = edge, wave = quarter (src lo/hi, dst lo/hi)
            const int e = base + l;
            const int ec = (e < M) ? e : (M - 1);
            const u32 sp = (u32)srcP[ec];
            const int row = (wv < 2) ? (int)(sp & 0x3FFFFFFFu) : dstP[ec];
            const uint4* gp = (const uint4*)(hbf + (size_t)row * 64 + (wv & 1) * 32);
            uint4* dp = (uint4*)(sU + l * 68 + wv * 16);
#pragma unroll
            for (int i = 0; i < 4; ++i) dp[i] = gp[i];
        }
        __syncthreads();

        // per-m-tile type info (wave-uniform uniformity flag)
        int rt[2][4];
        int bty[2];
        bool unif[2];
#pragma unroll
        for (int mi = 0; mi < 2; ++mi) {
            const int m = 2 * w0 + mi;
            const int t0 = sTy[m * 16];
            bool same = true;
#pragma unroll
            for (int r = 0; r < 4; ++r) {
                rt[mi][r] = sTy[m * 16 + quad * 4 + r];
                same = same && (rt[mi][r] == t0);
            }
            unif[mi] = (__ballot(same) == ~0ull);
            bty[mi] = t0 & 1;
        }

        // ---- layer 1: hidden = relu(MI @ W1 + b1) ----
#pragma unroll
        for (int mi = 0; mi < 2; ++mi) {
            const int m = 2 * w0 + mi;
            short8 a[4];
#pragma unroll
            for (int s = 0; s < 4; ++s)
                a[s] = *(const short8*)(sU + (m * 16 + l15) * 68 + s * 16 + quad * 4);
            if (unif[mi]) {
                const int t = bty[mi];
                f32x4 ac0 = vzero, ac1 = vzero;
#pragma unroll
                for (int s = 0; s < 4; ++s) {
                    ac0 = __builtin_amdgcn_mfma_f32_16x16x32_bf16(a[s], Bf1[t][s][0], ac0, 0, 0, 0);
                    ac1 = __builtin_amdgcn_mfma_f32_16x16x32_bf16(a[s], Bf1[t][s][1], ac1, 0, 0, 0);
                }
#pragma unroll
                for (int ni = 0; ni < 2; ++ni) {
                    const int c = (2 * w1i + ni) * 16 + l15;
#pragma unroll
                    for (int r = 0; r < 4; ++r) {
                        float v = (ni == 0) ? ac0[r] : ac1[r];
                        float hv = fmaxf(v + b1r[t][ni], 0.f);
                        ((u16*)sHid)[(m * 16 + quad * 4 + r) * 72 + c] = (u16)f2bf(hv);
                    }
                }
            } else {  // rare boundary tile: compute both types, per-row select
                f32x4 A0[2], A1[2];
                A0[0] = A0[1] = A1[0] = A1[1] = vzero;
#pragma unroll
                for (int s = 0; s < 4; ++s) {
                    A0[0] = __builtin_amdgcn_mfma_f32_16x16x32_bf16(a[s], Bf1[0][s][0], A0[0], 0, 0, 0);
                    A0[1] = __builtin_amdgcn_mfma_f32_16x16x32_bf16(a[s], Bf1[0][s][1], A0[1], 0, 0, 0);
                    A1[0] = __builtin_amdgcn_mfma_f32_16x16x32_bf16(a[s], Bf1[1][s][0], A1[0], 0, 0, 0);
                    A1[1] = __builtin_amdgcn_mfma_f32_16x16x32_bf16(a[s], Bf1[1][s][1], A1[1], 0, 0, 0);
                }
#pragma unroll
                for (int ni = 0; ni < 2; ++ni) {
                    const int c = (2 * w1i + ni) * 16 + l15;
#pragma unroll
                    for (int r = 0; r < 4; ++r) {
                        int ty = rt[mi][r] & 1;
                        float v = ty ? A1[ni][r] : A0[ni][r];
                        float hv = fmaxf(v + b1r[ty][ni], 0.f);
                        ((u16*)sHid)[(m * 16 + quad * 4 + r) * 72 + c] = (u16)f2bf(hv);
                    }
                }
            }
        }
        __syncthreads();  // hidden ready; sU (A) dead

        // ---- layer 2: msg = hidden @ W2 (+ b2 at write) ----
        f32x4 acc2[2][2];
#pragma unroll
        for (int mi = 0; mi < 2; ++mi) {
            const int m = 2 * w0 + mi;
            short8 ah[2];
#pragma unroll
            for (int s = 0; s < 2; ++s)
                ah[s] = *(const short8*)(sHid + (m * 16 + l15) * 36 + s * 16 + quad * 4);
            if (unif[mi]) {
                const int t = bty[mi];
                f32x4 ac0 = vzero, ac1 = vzero;
#pragma unroll
                for (int s = 0; s < 2; ++s) {
                    ac0 = __builtin_amdgcn_mfma_f32_16x16x32_bf16(ah[s], Bf2[t][s][0], ac0, 0, 0, 0);
                    ac1 = __builtin_amdgcn_mfma_f32_16x16x32_bf16(ah[s], Bf2[t][s][1], ac1, 0, 0, 0);
                }
                acc2[mi][0] = ac0;
                acc2[mi][1] = ac1;
            } else {
                f32x4 A0[2], A1[2];
                A0[0] = A0[1] = A1[0] = A1[1] = vzero;
#pragma unroll
                for (int s = 0; s < 2; ++s) {
                    A0[0] = __builtin_amdgcn_mfma_f32_16x16x32_bf16(ah[s], Bf2[0][s][0], A0[0], 0, 0, 0);
                    A0[1] = __builtin_amdgcn_mfma_f32_16x16x32_bf16(ah[s], Bf2[0][s][1], A0[1], 0, 0, 0);
                    A1[0] = __builtin_amdgcn_mfma_f32_16x16x32_bf16(ah[s], Bf2[1][s][0], A1[0], 0, 0, 0);
                    A1[1] = __builtin_amdgcn_mfma_f32_16x16x32_bf16(ah[s], Bf2[1][s][1], A1[1], 0, 0, 0);
                }
#pragma unroll
                for (int ni = 0; ni < 2; ++ni)
#pragma unroll
                    for (int r = 0; r < 4; ++r)
                        acc2[mi][ni][r] = (rt[mi][r] & 1) ? A1[ni][r] : A0[ni][r];
            }
        }
        // write msg (+b2) into sU region: [col][edge], stride 69 (A reads fenced by prev sync)
#pragma unroll
        for (int mi = 0; mi < 2; ++mi) {
            const int m = 2 * w0 + mi;
#pragma unroll
            for (int ni = 0; ni < 2; ++ni) {
                const int c = (2 * w1i + ni) * 16 + l15;
#pragma unroll
                for (int r = 0; r < 4; ++r) {
                    int ty = unif[mi] ? bty[mi] : (rt[mi][r] & 1);
                    ((float*)sU)[c * 69 + m * 16 + quad * 4 + r] = acc2[mi][ni][r] + b2r[ty][ni];
                }
            }
        }
        __syncthreads();
        // run-reduction in dst-sorted order: 64 cols x 4 chunks of 16 edges
        {
            const float* mf = (const float*)sU;
            const int c = tid & 63, q = tid >> 6;
            float aSum = 0.f;
            int cur = -1;
            for (int i = 0; i < 16; ++i) {
                int e = q * 16 + i;
                int d = sDst[e];
                if (d != cur) {
                    if (cur >= 0) unsafeAtomicAdd(agg + (size_t)cur * 64 + c, aSum);
                    cur = d;
                    aSum = 0.f;
                }
                if (d >= 0) aSum += mf[c * 69 + e];
            }
            if (cur >= 0) unsafeAtomicAdd(agg + (size_t)cur * 64 + c, aSum);
        }
    }
}

// ---------- GRU gate GEMM + fused elementwise combine (in-place h update) ----------
__global__ __launch_bounds__(256, 2) void k_gru_gemm(
    const float* __restrict__ agg, float* __restrict__ h, u16* __restrict__ hbf,
    const float* __restrict__ wi, const float* __restrict__ wh,
    const float* __restrict__ bi, const float* __restrict__ bh, int n_nodes) {
    __shared__ u32 sR[64 * 128];  // rz block: [kp][c], K=128, 32 KB
    __shared__ u32 sI[32 * 64];   // i_n block: K=64 (agg part)
    __shared__ u32 sH[32 * 64];   // h_n block: K=64 (h part)
    __shared__ u32 sAT[64 * 20];  // A = [agg|h] k-pair packed, 16 nodes
    __shared__ u32 sG[16 * 128];  // gate pre-activations, bf16 pairs [node][pair]
    __shared__ float sBC[256];

    const int tid = threadIdx.x;
    for (int u = tid; u < 64 * 128; u += 256) {
        int kp = u >> 7, c = u & 127;
        int k0 = 2 * kp;
        float v0 = (k0 < 64) ? wi[k0 * 192 + c] : wh[(k0 - 64) * 192 + c];
        float v1 = (k0 + 1 < 64) ? wi[(k0 + 1) * 192 + c] : wh[(k0 + 1 - 64) * 192 + c];
        sR[u] = pk(v0, v1);
    }
    for (int u = tid; u < 32 * 64; u += 256) {
        int kp = u >> 6, c = u & 63;
        sI[u] = pk(wi[(2 * kp) * 192 + 128 + c], wi[(2 * kp + 1) * 192 + 128 + c]);
        sH[u] = pk(wh[(2 * kp) * 192 + 128 + c], wh[(2 * kp + 1) * 192 + 128 + c]);
    }
    if (tid < 256) sBC[tid] = (tid < 128) ? (bi[tid] + bh[tid]) : ((tid < 192) ? bi[tid] : bh[tid - 64]);

    const int jq = tid & 63;
    const int eg = tid >> 6;
    const int n0 = eg * 4;
    const int n_tiles = (n_nodes + 15) >> 4;
    for (int tile = blockIdx.x; tile < n_tiles; tile += gridDim.x) {
        const int nb = tile << 4;
        __syncthreads();
#pragma unroll
        for (int q = 0; q < 4; ++q) {  // stage A (16 nodes x 64 kp)
            int u = tid + q * 256;
            int kp = u >> 4, n = u & 15;
            int node = nb + n;
            float2 v = make_float2(0.f, 0.f);
            if (node < n_nodes) {
                const float* p = (kp < 32) ? (agg + (size_t)node * 64 + 2 * kp)
                                           : (h + (size_t)node * 64 + 2 * kp - 64);
                v = *(const float2*)p;
            }
            sAT[kp * 20 + n] = pk(v.x, v.y);
        }
        __syncthreads();
        float acc[4][4] = {};
        if (jq < 32) {
            const int c0 = jq * 4;
#pragma unroll 2
            for (int kp = 0; kp < 64; ++kp) {
                uint4 mi = *(const uint4*)(sAT + kp * 20 + n0);
                uint4 wq = *(const uint4*)(sR + kp * 128 + c0);
                fma_4e4j(mi, wq, acc);
            }
        } else if (jq < 48) {
            const int c0 = (jq - 32) * 4;
#pragma unroll 2
            for (int kp = 0; kp < 32; ++kp) {
                uint4 mi = *(const uint4*)(sAT + kp * 20 + n0);
                uint4 wq = *(const uint4*)(sI + kp * 64 + c0);
                fma_4e4j(mi, wq, acc);
            }
        } else {
            const int c0 = (jq - 48) * 4;
#pragma unroll 2
            for (int kp = 0; kp < 32; ++kp) {
                uint4 mi = *(const uint4*)(sAT + (32 + kp) * 20 + n0);
                uint4 wq = *(const uint4*)(sH + kp * 64 + c0);
                fma_4e4j(mi, wq, acc);
            }
        }
        const int cbase = (jq < 32) ? jq * 4 : ((jq < 48) ? 128 + (jq - 32) * 4 : 192 + (jq - 48) * 4);
#pragma unroll
        for (int n = 0; n < 4; ++n) {
            int node = nb + n0 + n;
            if (node >= n_nodes) continue;
            float v0 = acc[n][0] + sBC[cbase + 0];
            float v1 = acc[n][1] + sBC[cbase + 1];
            float v2 = acc[n][2] + sBC[cbase + 2];
            float v3 = acc[n][3] + sBC[cbase + 3];
            u32* gp = sG + (n0 + n) * 128 + (cbase >> 1);
            gp[0] = pk(v0, v1);
            gp[1] = pk(v2, v3);
        }
        __syncthreads();
        // fused GRU combine: 16 nodes x 64 cols
        const u16* g16 = (const u16*)sG;
#pragma unroll
        for (int qq = 0; qq < 4; ++qq) {
            int idx = tid + qq * 256;
            int nl = idx >> 6, j = idx & 63;
            int node = nb + nl;
            if (node < n_nodes) {
                const u16* g = g16 + nl * 256;
                float rs = bfu(g[j]), zs = bfu(g[64 + j]), in_ = bfu(g[128 + j]), hn = bfu(g[192 + j]);
                float r = 1.f / (1.f + __expf(-rs));
                float z = 1.f / (1.f + __expf(-zs));
                float nn2 = tanhf(fmaf(r, hn, in_));
                float hv = h[(size_t)node * 64 + j];
                float nh = (1.f - z) * nn2 + z * hv;
                h[(size_t)node * 64 + j] = nh;
                hbf[(size_t)node * 64 + j] = (u16)f2bf(nh);
            }
        }
    }
}

// ---------- readout + data-qubit correction (wave per node) ----------
__global__ void k_readout(const float* __restrict__ h, const float* __restrict__ x,
                          const int* __restrict__ node_type, const float* __restrict__ w1,
                          const float* __restrict__ b1, const float* __restrict__ w2,
                          const float* __restrict__ b2, float* __restrict__ out, int n_nodes) {
    const int lane = threadIdx.x & 63;
    const int node = blockIdx.x * 4 + (threadIdx.x >> 6);
    if (node >= n_nodes) return;
    float hv = h[(size_t)node * 64 + lane];
    float acc = b1[lane];
    for (int k = 0; k < 64; ++k) acc = fmaf(__shfl(hv, k), w1[k * 64 + lane], acc);
    float t = fmaxf(acc, 0.f) * w2[lane];
#pragma unroll
    for (int off = 32; off > 0; off >>= 1) t += __shfl_xor(t, off);
    if (lane == 0) {
        float o = t + b2[0];
        out[node] = (node_type[node] == 0) ? (x[node * 4] + o) : 0.f;
    }
}

extern "C" void kernel_launch(void* const* d_in, const int* in_sizes, int n_in, void* d_out,
                              int out_size, void* d_ws, size_t ws_size, hipStream_t stream) {
    const float* x = (const float*)d_in[0];
    const int* node_type = (const int*)d_in[1];
    const int* edge_index = (const int*)d_in[2];
    const int* edge_type = (const int*)d_in[3];
    const float* in_w = (const float*)d_in[4];
    const float* in_b = (const float*)d_in[5];
    const float* ln_g = (const float*)d_in[6];
    const float* ln_b = (const float*)d_in[7];
    const float* mlp_w1 = (const float*)d_in[8];
    const float* mlp_b1 = (const float*)d_in[9];
    const float* mlp_w2 = (const float*)d_in[10];
    const float* mlp_b2 = (const float*)d_in[11];
    const float* gru_wi = (const float*)d_in[12];
    const float* gru_wh = (const float*)d_in[13];
    const float* gru_bi = (const float*)d_in[14];
    const float* gru_bh = (const float*)d_in[15];
    const float* ro_w1 = (const float*)d_in[16];
    const float* ro_b1 = (const float*)d_in[17];
    const float* ro_w2 = (const float*)d_in[18];
    const float* ro_b2 = (const float*)d_in[19];

    const int N = in_sizes[1];  // nodes
    const int M = in_sizes[3];  // edges
    const int* src = edge_index;
    const int* dst = edge_index + M;

    // ws layout: h (N*256B) | agg (N*256B) | hbf (N*128B) | off (2N*4) | part (4KB) | srcP | dstP
    char* wsb = (char*)d_ws;
    float* h = (float*)wsb;
    float* agg = (float*)(wsb + (size_t)N * 256);
    u16* hbf = (u16*)(wsb + (size_t)N * 512);
    int* off = (int*)(wsb + (size_t)N * 640);
    int* part = (int*)(wsb + (size_t)N * 640 + (size_t)2 * N * 4);
    int* srcP = (int*)(wsb + (size_t)N * 640 + (size_t)2 * N * 4 + 4096);
    int* dstP = srcP + M;

    const int NB = 2 * N;                 // sort bins = type*N + dst
    const int nb = (NB + 1023) / 1024;

    // build (type,dst)-sorted edge permutation (reused by all 3 layers)
    hipMemsetAsync(off, 0, (size_t)NB * sizeof(int), stream);
    k_hist<<<(M + 255) / 256, 256, 0, stream>>>(dst, edge_type, off, M, N);
    k_scan1<<<nb, 1024, 0, stream>>>(off, part, NB);
    k_scan2<<<1, 64, 0, stream>>>(part, nb);
    k_scan3<<<nb, 1024, 0, stream>>>(off, part, NB);
    k_scatter<<<(M + 255) / 256, 256, 0, stream>>>(src, dst, edge_type, off, srcP, dstP, M, N);

    k_input_proj<<<(N + 3) / 4, 256, 0, stream>>>(x, in_w, in_b, ln_g, ln_b, h, hbf, N);
    for (int l = 0; l < 3; ++l) {
        hipMemsetAsync(agg, 0, (size_t)N * 64 * sizeof(float), stream);
        k_edge_mlp<<<512, 256, 0, stream>>>(hbf, srcP, dstP,
                                            mlp_w1 + (size_t)l * 2 * 128 * 64,
                                            mlp_b1 + (size_t)l * 2 * 64,
                                            mlp_w2 + (size_t)l * 2 * 64 * 64,
                                            mlp_b2 + (size_t)l * 2 * 64, agg, M);
        k_gru_gemm<<<512, 256, 0, stream>>>(agg, h, hbf, gru_wi + (size_t)l * 64 * 192,
                                            gru_wh + (size_t)l * 64 * 192,
                                            gru_bi + (size_t)l * 192, gru_bh + (size_t)l * 192, N);
    }
    k_readout<<<(N + 3) / 4, 256, 0, stream>>>(h, x, node_type, ro_w1, ro_b1, ro_w2, ro_b2,
                                               (float*)d_out, N);
}

// Round 4
// 1647.172 us; speedup vs baseline: 4.5197x; 4.5197x over previous
//
#include <hip/hip_runtime.h>

typedef unsigned int u32;
typedef unsigned short u16;
typedef unsigned long long u64;

using short8 = __attribute__((ext_vector_type(8))) short;
using f32x4  = __attribute__((ext_vector_type(4))) float;

// ---------- bf16 helpers (manual, RTN-even) ----------
__device__ __forceinline__ u32 f2bf(float f) {
    u32 u = __float_as_uint(f);
    return (u + 0x7fffu + ((u >> 16) & 1u)) >> 16;
}
__device__ __forceinline__ u32 pk(float a, float b) {
    return f2bf(a) | (f2bf(b) << 16);
}
__device__ __forceinline__ float bflo(u32 u) { return __uint_as_float(u << 16); }
__device__ __forceinline__ float bfhi(u32 u) { return __uint_as_float(u & 0xffff0000u); }
__device__ __forceinline__ float bfu(u16 u) { return __uint_as_float(((u32)u) << 16); }

union U8 { u32 u[4]; short8 v; };

// 4 x 4 x 2k fp32 FMA block (GRU kernel)
__device__ __forceinline__ void fma_4e4j(const uint4& mi, const uint4& wq, float (&acc)[4][4]) {
    const u32* mp = (const u32*)&mi;
    const u32* wp = (const u32*)&wq;
    float wl[4], wh[4];
#pragma unroll
    for (int j = 0; j < 4; ++j) { wl[j] = bflo(wp[j]); wh[j] = bfhi(wp[j]); }
#pragma unroll
    for (int e = 0; e < 4; ++e) {
        float ml = bflo(mp[e]), mh = bfhi(mp[e]);
#pragma unroll
        for (int j = 0; j < 4; ++j)
            acc[e][j] = fmaf(mh, wh[j], fmaf(ml, wl[j], acc[e][j]));
    }
}

// ---------- input projection + LayerNorm + ReLU (wave per node) ----------
__global__ void k_input_proj(const float* __restrict__ x, const float* __restrict__ in_w,
                             const float* __restrict__ in_b, const float* __restrict__ ln_g,
                             const float* __restrict__ ln_b, float* __restrict__ h,
                             u16* __restrict__ hbf, int n_nodes) {
    const int lane = threadIdx.x & 63;
    const int node = blockIdx.x * 4 + (threadIdx.x >> 6);
    if (node >= n_nodes) return;
    float acc = in_b[lane];
#pragma unroll
    for (int k = 0; k < 4; ++k) acc = fmaf(x[node * 4 + k], in_w[k * 64 + lane], acc);
    float s = acc;
#pragma unroll
    for (int off = 32; off > 0; off >>= 1) s += __shfl_xor(s, off);
    float mu = s * (1.f / 64.f);
    float d = acc - mu;
    float vs = d * d;
#pragma unroll
    for (int off = 32; off > 0; off >>= 1) vs += __shfl_xor(vs, off);
    float inv = rsqrtf(vs * (1.f / 64.f) + 1e-5f);
    float hv = fmaxf(d * inv * ln_g[lane] + ln_b[lane], 0.f);
    h[(size_t)node * 64 + lane] = hv;
    hbf[(size_t)node * 64 + lane] = (u16)f2bf(hv);
}

// ---------- (type,dst)-sort: histogram, scan, scatter ----------
__global__ void k_hist(const int* __restrict__ dst, const int* __restrict__ ety,
                       int* __restrict__ cnt, int M, int N) {
    int i = blockIdx.x * 256 + threadIdx.x;
    if (i < M) atomicAdd(&cnt[(ety[i] & 1) * N + dst[i]], 1);
}

__global__ void k_scan1(int* __restrict__ data, int* __restrict__ part, int N) {
    __shared__ int s[1024];
    const int t = threadIdx.x;
    const int i = blockIdx.x * 1024 + t;
    int v = (i < N) ? data[i] : 0;
    s[t] = v;
    __syncthreads();
#pragma unroll
    for (int d = 1; d < 1024; d <<= 1) {
        int x = (t >= d) ? s[t - d] : 0;
        __syncthreads();
        s[t] += x;
        __syncthreads();
    }
    if (i < N) data[i] = s[t] - v;  // exclusive
    if (t == 1023) part[blockIdx.x] = s[1023];
}

__global__ void k_scan2(int* __restrict__ part, int nb) {
    if (threadIdx.x == 0 && blockIdx.x == 0) {
        int a = 0;
        for (int i = 0; i < nb; ++i) { int t = part[i]; part[i] = a; a += t; }
    }
}

__global__ void k_scan3(int* __restrict__ data, const int* __restrict__ part, int N) {
    int i = blockIdx.x * 1024 + threadIdx.x;
    if (i < N) data[i] += part[blockIdx.x];
}

__global__ void k_savet0(const int* __restrict__ off, int N, int* __restrict__ slot) {
    if (threadIdx.x == 0 && blockIdx.x == 0) slot[0] = off[N];  // # of type-0 edges
}

__global__ void k_scatter(const int* __restrict__ src, const int* __restrict__ dst,
                          const int* __restrict__ ety, int* __restrict__ cursor,
                          int* __restrict__ srcP, int* __restrict__ dstP, int M, int N) {
    int e = blockIdx.x * 256 + threadIdx.x;
    if (e < M) {
        int d = dst[e];
        int t = ety[e] & 1;
        int pos = atomicAdd(&cursor[t * N + d], 1);
        srcP[pos] = src[e] & 0x3FFFFFFF;
        dstP[pos] = d;
    }
}

// ---------- edge message MLP: one tile per wave, zero barriers ----------
// Edges sorted by (type,dst). Blocks 0..half-1 handle type 0, rest type 1;
// type is block-static so W1/W2 fragments live in registers with static
// indexing. A-fragments loaded directly from global (16B/lane, A-layout).
// Hidden + msg round-trip through a PRIVATE per-wave LDS region (same-wave DS
// ordering -> no barriers). Run-reduced scatter: one atomic per (run, col).
__global__ __launch_bounds__(256, 2) void k_edge_mlp(
    const u16* __restrict__ hbf, const int* __restrict__ srcP, const int* __restrict__ dstP,
    const int* __restrict__ t0p, const float* __restrict__ w1, const float* __restrict__ b1,
    const float* __restrict__ w2, const float* __restrict__ b2,
    float* __restrict__ agg, int M) {
    __shared__ u16 sHid[4][4608];            // per-wave: hidden (stride 72) / msg (stride 70)
    __shared__ int sMS[4][64], sMD[4][64];   // per-wave meta

    const int tid = threadIdx.x;
    const int l = tid & 63, wv = tid >> 6;
    const int l15 = l & 15, quad = l >> 4;
    const f32x4 vz = {0.f, 0.f, 0.f, 0.f};

    const int T0 = *t0p;
    const int half = gridDim.x >> 1;
    const int ty = (blockIdx.x >= half) ? 1 : 0;
    const int bi = ty ? (int)blockIdx.x - half : (int)blockIdx.x;

    const int n_tiles = (M + 63) >> 6;
    const int tlo = ty ? (T0 >> 6) : 0;
    const int thi = ty ? n_tiles : ((T0 + 63) >> 6);
    const int lo = ty ? T0 : 0;
    const int hi = ty ? M : T0;
    const int range = thi - tlo;
    const int per = (range + half - 1) / half;
    const int c0 = tlo + bi * per;
    const int c1 = min(c0 + per, thi);

    // ---- register B fragments + biases for this block's type (static idx) ----
    short8 Bf1[4][4], Bf2[2][4];
    float b1r[4], b2r[4];
#pragma unroll
    for (int ni = 0; ni < 4; ++ni) {
        const int c = ni * 16 + l15;
        b1r[ni] = b1[ty * 64 + c];
        b2r[ni] = b2[ty * 64 + c];
#pragma unroll
        for (int s = 0; s < 4; ++s) {
            U8 tmp;
            const float* wp = w1 + (size_t)ty * 8192 + (size_t)(s * 32 + quad * 8) * 64 + c;
#pragma unroll
            for (int jp = 0; jp < 4; ++jp) tmp.u[jp] = pk(wp[(2 * jp) * 64], wp[(2 * jp + 1) * 64]);
            Bf1[s][ni] = tmp.v;
        }
#pragma unroll
        for (int s = 0; s < 2; ++s) {
            U8 tmp;
            const float* wp = w2 + (size_t)ty * 4096 + (size_t)(s * 32 + quad * 8) * 64 + c;
#pragma unroll
            for (int jp = 0; jp < 4; ++jp) tmp.u[jp] = pk(wp[(2 * jp) * 64], wp[(2 * jp + 1) * 64]);
            Bf2[s][ni] = tmp.v;
        }
    }

    u16* hid = sHid[wv];
    int* mS = sMS[wv];
    int* mD = sMD[wv];

    for (int tile = c0 + wv; tile < c1; tile += 4) {
        const int base = tile << 6;
        {   // meta (own wave's LDS only)
            int e = base + l;
            int ec = (e < M) ? e : (M - 1);
            mS[l] = srcP[ec];
            mD[l] = dstP[ec];
        }
        // rows for this lane's A fragments (cross-lane via per-wave LDS)
        int rs[4], rd[4];
#pragma unroll
        for (int mi = 0; mi < 4; ++mi) {
            rs[mi] = mS[mi * 16 + l15];
            rd[mi] = mD[mi * 16 + l15];
        }
        // A gather: 16 x dwordx4, direct A-layout (k = s*32 + quad*8 .. +8)
        short8 a1[4][4];
#pragma unroll
        for (int mi = 0; mi < 4; ++mi)
#pragma unroll
            for (int s = 0; s < 4; ++s) {
                const int row = (s < 2) ? rs[mi] : rd[mi];
                a1[mi][s] = *(const short8*)(hbf + (size_t)row * 64 + (s & 1) * 32 + quad * 8);
            }
        // ---- layer 1: hidden = relu(A @ W1 + b1) ----
#pragma unroll
        for (int mi = 0; mi < 4; ++mi) {
            f32x4 acc[4] = {vz, vz, vz, vz};
#pragma unroll
            for (int s = 0; s < 4; ++s)
#pragma unroll
                for (int ni = 0; ni < 4; ++ni)
                    acc[ni] = __builtin_amdgcn_mfma_f32_16x16x32_bf16(a1[mi][s], Bf1[s][ni], acc[ni], 0, 0, 0);
#pragma unroll
            for (int ni = 0; ni < 4; ++ni) {
                const int c = ni * 16 + l15;
#pragma unroll
                for (int r = 0; r < 4; ++r) {
                    float hv = fmaxf(acc[ni][r] + b1r[ni], 0.f);
                    hid[(mi * 16 + quad * 4 + r) * 72 + c] = (u16)f2bf(hv);
                }
            }
        }
        // ---- layer 2: msg = hidden @ W2 + b2 ----
        f32x4 acc2[4][4];
#pragma unroll
        for (int mi = 0; mi < 4; ++mi) {
            short8 a2a = *(const short8*)(hid + (mi * 16 + l15) * 72 + quad * 8);
            short8 a2b = *(const short8*)(hid + (mi * 16 + l15) * 72 + 32 + quad * 8);
#pragma unroll
            for (int ni = 0; ni < 4; ++ni) {
                f32x4 t = __builtin_amdgcn_mfma_f32_16x16x32_bf16(a2a, Bf2[0][ni], vz, 0, 0, 0);
                acc2[mi][ni] = __builtin_amdgcn_mfma_f32_16x16x32_bf16(a2b, Bf2[1][ni], t, 0, 0, 0);
            }
        }
        __asm__ volatile("s_waitcnt lgkmcnt(0)");  // hidden reads drained; reuse region for msg
        // msg (bf16 + b2) -> [col][edge], stride 70 (same-wave DS order => no barrier)
#pragma unroll
        for (int mi = 0; mi < 4; ++mi)
#pragma unroll
            for (int ni = 0; ni < 4; ++ni) {
                const int c = ni * 16 + l15;
                const int e0 = mi * 16 + quad * 4;
                float bb = b2r[ni];
                *(u32*)(hid + c * 70 + e0) = pk(acc2[mi][ni][0] + bb, acc2[mi][ni][1] + bb);
                *(u32*)(hid + c * 70 + e0 + 2) = pk(acc2[mi][ni][2] + bb, acc2[mi][ni][3] + bb);
            }
        // ---- run-reduction (lane = column), 1 atomic per (run, col) ----
        {
            const int c = l;
            float a = 0.f;
            int cur = -1;
            for (int i = 0; i < 64; i += 2) {
                u32 pm = *(const u32*)(hid + c * 70 + i);
                int2 dd = *(const int2*)(mD + i);
                int eg = base + i;
                if (eg >= lo && eg < hi) {
                    if (dd.x != cur) {
                        if (cur >= 0) unsafeAtomicAdd(agg + (size_t)cur * 64 + c, a);
                        cur = dd.x; a = 0.f;
                    }
                    a += bflo(pm);
                }
                if (eg + 1 >= lo && eg + 1 < hi) {
                    if (dd.y != cur) {
                        if (cur >= 0) unsafeAtomicAdd(agg + (size_t)cur * 64 + c, a);
                        cur = dd.y; a = 0.f;
                    }
                    a += bfhi(pm);
                }
            }
            if (cur >= 0) unsafeAtomicAdd(agg + (size_t)cur * 64 + c, a);
        }
    }
}

// ---------- GRU gate GEMM + fused elementwise combine (in-place h update) ----------
__global__ __launch_bounds__(256, 2) void k_gru_gemm(
    const float* __restrict__ agg, float* __restrict__ h, u16* __restrict__ hbf,
    const float* __restrict__ wi, const float* __restrict__ wh,
    const float* __restrict__ bi, const float* __restrict__ bh, int n_nodes) {
    __shared__ u32 sR[64 * 128];
    __shared__ u32 sI[32 * 64];
    __shared__ u32 sH[32 * 64];
    __shared__ u32 sAT[64 * 20];
    __shared__ u32 sG[16 * 128];
    __shared__ float sBC[256];

    const int tid = threadIdx.x;
    for (int u = tid; u < 64 * 128; u += 256) {
        int kp = u >> 7, c = u & 127;
        int k0 = 2 * kp;
        float v0 = (k0 < 64) ? wi[k0 * 192 + c] : wh[(k0 - 64) * 192 + c];
        float v1 = (k0 + 1 < 64) ? wi[(k0 + 1) * 192 + c] : wh[(k0 + 1 - 64) * 192 + c];
        sR[u] = pk(v0, v1);
    }
    for (int u = tid; u < 32 * 64; u += 256) {
        int kp = u >> 6, c = u & 63;
        sI[u] = pk(wi[(2 * kp) * 192 + 128 + c], wi[(2 * kp + 1) * 192 + 128 + c]);
        sH[u] = pk(wh[(2 * kp) * 192 + 128 + c], wh[(2 * kp + 1) * 192 + 128 + c]);
    }
    if (tid < 256) sBC[tid] = (tid < 128) ? (bi[tid] + bh[tid]) : ((tid < 192) ? bi[tid] : bh[tid - 64]);

    const int jq = tid & 63;
    const int eg = tid >> 6;
    const int n0 = eg * 4;
    const int n_tiles = (n_nodes + 15) >> 4;
    for (int tile = blockIdx.x; tile < n_tiles; tile += gridDim.x) {
        const int nb = tile << 4;
        __syncthreads();
#pragma unroll
        for (int q = 0; q < 4; ++q) {
            int u = tid + q * 256;
            int kp = u >> 4, n = u & 15;
            int node = nb + n;
            float2 v = make_float2(0.f, 0.f);
            if (node < n_nodes) {
                const float* p = (kp < 32) ? (agg + (size_t)node * 64 + 2 * kp)
                                           : (h + (size_t)node * 64 + 2 * kp - 64);
                v = *(const float2*)p;
            }
            sAT[kp * 20 + n] = pk(v.x, v.y);
        }
        __syncthreads();
        float acc[4][4] = {};
        if (jq < 32) {
            const int c0 = jq * 4;
#pragma unroll 2
            for (int kp = 0; kp < 64; ++kp) {
                uint4 mi = *(const uint4*)(sAT + kp * 20 + n0);
                uint4 wq = *(const uint4*)(sR + kp * 128 + c0);
                fma_4e4j(mi, wq, acc);
            }
        } else if (jq < 48) {
            const int c0 = (jq - 32) * 4;
#pragma unroll 2
            for (int kp = 0; kp < 32; ++kp) {
                uint4 mi = *(const uint4*)(sAT + kp * 20 + n0);
                uint4 wq = *(const uint4*)(sI + kp * 64 + c0);
                fma_4e4j(mi, wq, acc);
            }
        } else {
            const int c0 = (jq - 48) * 4;
#pragma unroll 2
            for (int kp = 0; kp < 32; ++kp) {
                uint4 mi = *(const uint4*)(sAT + (32 + kp) * 20 + n0);
                uint4 wq = *(const uint4*)(sH + kp * 64 + c0);
                fma_4e4j(mi, wq, acc);
            }
        }
        const int cbase = (jq < 32) ? jq * 4 : ((jq < 48) ? 128 + (jq - 32) * 4 : 192 + (jq - 48) * 4);
#pragma unroll
        for (int n = 0; n < 4; ++n) {
            int node = nb + n0 + n;
            if (node >= n_nodes) continue;
            float v0 = acc[n][0] + sBC[cbase + 0];
            float v1 = acc[n][1] + sBC[cbase + 1];
            float v2 = acc[n][2] + sBC[cbase + 2];
            float v3 = acc[n][3] + sBC[cbase + 3];
            u32* gp = sG + (n0 + n) * 128 + (cbase >> 1);
            gp[0] = pk(v0, v1);
            gp[1] = pk(v2, v3);
        }
        __syncthreads();
        const u16* g16 = (const u16*)sG;
#pragma unroll
        for (int qq = 0; qq < 4; ++qq) {
            int idx = tid + qq * 256;
            int nl = idx >> 6, j = idx & 63;
            int node = nb + nl;
            if (node < n_nodes) {
                const u16* g = g16 + nl * 256;
                float rs = bfu(g[j]), zs = bfu(g[64 + j]), in_ = bfu(g[128 + j]), hn = bfu(g[192 + j]);
                float r = 1.f / (1.f + __expf(-rs));
                float z = 1.f / (1.f + __expf(-zs));
                float nn2 = tanhf(fmaf(r, hn, in_));
                float hv = h[(size_t)node * 64 + j];
                float nh = (1.f - z) * nn2 + z * hv;
                h[(size_t)node * 64 + j] = nh;
                hbf[(size_t)node * 64 + j] = (u16)f2bf(nh);
            }
        }
    }
}

// ---------- readout + data-qubit correction (wave per node) ----------
__global__ void k_readout(const float* __restrict__ h, const float* __restrict__ x,
                          const int* __restrict__ node_type, const float* __restrict__ w1,
                          const float* __restrict__ b1, const float* __restrict__ w2,
                          const float* __restrict__ b2, float* __restrict__ out, int n_nodes) {
    const int lane = threadIdx.x & 63;
    const int node = blockIdx.x * 4 + (threadIdx.x >> 6);
    if (node >= n_nodes) return;
    float hv = h[(size_t)node * 64 + lane];
    float acc = b1[lane];
    for (int k = 0; k < 64; ++k) acc = fmaf(__shfl(hv, k), w1[k * 64 + lane], acc);
    float t = fmaxf(acc, 0.f) * w2[lane];
#pragma unroll
    for (int off = 32; off > 0; off >>= 1) t += __shfl_xor(t, off);
    if (lane == 0) {
        float o = t + b2[0];
        out[node] = (node_type[node] == 0) ? (x[node * 4] + o) : 0.f;
    }
}

extern "C" void kernel_launch(void* const* d_in, const int* in_sizes, int n_in, void* d_out,
                              int out_size, void* d_ws, size_t ws_size, hipStream_t stream) {
    const float* x = (const float*)d_in[0];
    const int* node_type = (const int*)d_in[1];
    const int* edge_index = (const int*)d_in[2];
    const int* edge_type = (const int*)d_in[3];
    const float* in_w = (const float*)d_in[4];
    const float* in_b = (const float*)d_in[5];
    const float* ln_g = (const float*)d_in[6];
    const float* ln_b = (const float*)d_in[7];
    const float* mlp_w1 = (const float*)d_in[8];
    const float* mlp_b1 = (const float*)d_in[9];
    const float* mlp_w2 = (const float*)d_in[10];
    const float* mlp_b2 = (const float*)d_in[11];
    const float* gru_wi = (const float*)d_in[12];
    const float* gru_wh = (const float*)d_in[13];
    const float* gru_bi = (const float*)d_in[14];
    const float* gru_bh = (const float*)d_in[15];
    const float* ro_w1 = (const float*)d_in[16];
    const float* ro_b1 = (const float*)d_in[17];
    const float* ro_w2 = (const float*)d_in[18];
    const float* ro_b2 = (const float*)d_in[19];

    const int N = in_sizes[1];  // nodes
    const int M = in_sizes[3];  // edges
    const int* src = edge_index;
    const int* dst = edge_index + M;

    // ws: h (N*256B) | agg (N*256B) | hbf (N*128B) | off (2N*4) | part (4KB) | srcP | dstP
    char* wsb = (char*)d_ws;
    float* h = (float*)wsb;
    float* agg = (float*)(wsb + (size_t)N * 256);
    u16* hbf = (u16*)(wsb + (size_t)N * 512);
    int* off = (int*)(wsb + (size_t)N * 640);
    int* part = (int*)(wsb + (size_t)N * 640 + (size_t)2 * N * 4);
    int* srcP = (int*)(wsb + (size_t)N * 640 + (size_t)2 * N * 4 + 4096);
    int* dstP = srcP + M;
    int* t0slot = part + 1000;

    const int NB = 2 * N;
    const int nb = (NB + 1023) / 1024;

    // build (type,dst)-sorted edge permutation (reused by all 3 layers)
    hipMemsetAsync(off, 0, (size_t)NB * sizeof(int), stream);
    k_hist<<<(M + 255) / 256, 256, 0, stream>>>(dst, edge_type, off, M, N);
    k_scan1<<<nb, 1024, 0, stream>>>(off, part, NB);
    k_scan2<<<1, 64, 0, stream>>>(part, nb);
    k_scan3<<<nb, 1024, 0, stream>>>(off, part, NB);
    k_savet0<<<1, 64, 0, stream>>>(off, N, t0slot);
    k_scatter<<<(M + 255) / 256, 256, 0, stream>>>(src, dst, edge_type, off, srcP, dstP, M, N);

    k_input_proj<<<(N + 3) / 4, 256, 0, stream>>>(x, in_w, in_b, ln_g, ln_b, h, hbf, N);
    for (int l = 0; l < 3; ++l) {
        hipMemsetAsync(agg, 0, (size_t)N * 64 * sizeof(float), stream);
        k_edge_mlp<<<1024, 256, 0, stream>>>(hbf, srcP, dstP, t0slot,
                                             mlp_w1 + (size_t)l * 2 * 128 * 64,
                                             mlp_b1 + (size_t)l * 2 * 64,
                                             mlp_w2 + (size_t)l * 2 * 64 * 64,
                                             mlp_b2 + (size_t)l * 2 * 64, agg, M);
        k_gru_gemm<<<512, 256, 0, stream>>>(agg, h, hbf, gru_wi + (size_t)l * 64 * 192,
                                            gru_wh + (size_t)l * 64 * 192,
                                            gru_bi + (size_t)l * 192, gru_bh + (size_t)l * 192, N);
    }
    k_readout<<<(N + 3) / 4, 256, 0, stream>>>(h, x, node_type, ro_w1, ro_b1, ro_w2, ro_b2,
                                               (float*)d_out, N);
}

// Round 5
// 1096.300 us; speedup vs baseline: 6.7908x; 1.5025x over previous
//
#include <hip/hip_runtime.h>

typedef unsigned int u32;
typedef unsigned short u16;
typedef unsigned long long u64;

using short8 = __attribute__((ext_vector_type(8))) short;
using f32x4  = __attribute__((ext_vector_type(4))) float;

// ---------- bf16 helpers (manual, RTN-even) ----------
__device__ __forceinline__ u32 f2bf(float f) {
    u32 u = __float_as_uint(f);
    return (u + 0x7fffu + ((u >> 16) & 1u)) >> 16;
}
__device__ __forceinline__ u32 pk(float a, float b) {
    return f2bf(a) | (f2bf(b) << 16);
}
__device__ __forceinline__ float bflo(u32 u) { return __uint_as_float(u << 16); }
__device__ __forceinline__ float bfhi(u32 u) { return __uint_as_float(u & 0xffff0000u); }
__device__ __forceinline__ float bfu(u16 u) { return __uint_as_float(((u32)u) << 16); }

union U8 { u32 u[4]; short8 v; };

// ---------- input projection + LayerNorm + ReLU (wave per node) ----------
__global__ void k_input_proj(const float* __restrict__ x, const float* __restrict__ in_w,
                             const float* __restrict__ in_b, const float* __restrict__ ln_g,
                             const float* __restrict__ ln_b, float* __restrict__ h,
                             u16* __restrict__ hbf, int n_nodes) {
    const int lane = threadIdx.x & 63;
    const int node = blockIdx.x * 4 + (threadIdx.x >> 6);
    if (node >= n_nodes) return;
    float acc = in_b[lane];
#pragma unroll
    for (int k = 0; k < 4; ++k) acc = fmaf(x[node * 4 + k], in_w[k * 64 + lane], acc);
    float s = acc;
#pragma unroll
    for (int off = 32; off > 0; off >>= 1) s += __shfl_xor(s, off);
    float mu = s * (1.f / 64.f);
    float d = acc - mu;
    float vs = d * d;
#pragma unroll
    for (int off = 32; off > 0; off >>= 1) vs += __shfl_xor(vs, off);
    float inv = rsqrtf(vs * (1.f / 64.f) + 1e-5f);
    float hv = fmaxf(d * inv * ln_g[lane] + ln_b[lane], 0.f);
    h[(size_t)node * 64 + lane] = hv;
    hbf[(size_t)node * 64 + lane] = (u16)f2bf(hv);
}

// ---------- (type,dst)-sort: histogram, scan, scatter ----------
__global__ void k_hist(const int* __restrict__ dst, const int* __restrict__ ety,
                       int* __restrict__ cnt, int M, int N) {
    int i = blockIdx.x * 256 + threadIdx.x;
    if (i < M) atomicAdd(&cnt[(ety[i] & 1) * N + dst[i]], 1);
}

__global__ void k_scan1(int* __restrict__ data, int* __restrict__ part, int N) {
    __shared__ int s[1024];
    const int t = threadIdx.x;
    const int i = blockIdx.x * 1024 + t;
    int v = (i < N) ? data[i] : 0;
    s[t] = v;
    __syncthreads();
#pragma unroll
    for (int d = 1; d < 1024; d <<= 1) {
        int x = (t >= d) ? s[t - d] : 0;
        __syncthreads();
        s[t] += x;
        __syncthreads();
    }
    if (i < N) data[i] = s[t] - v;  // exclusive
    if (t == 1023) part[blockIdx.x] = s[1023];
}

__global__ void k_scan2(int* __restrict__ part, int nb) {
    if (threadIdx.x == 0 && blockIdx.x == 0) {
        int a = 0;
        for (int i = 0; i < nb; ++i) { int t = part[i]; part[i] = a; a += t; }
    }
}

__global__ void k_scan3(int* __restrict__ data, const int* __restrict__ part, int N) {
    int i = blockIdx.x * 1024 + threadIdx.x;
    if (i < N) data[i] += part[blockIdx.x];
}

__global__ void k_savet0(const int* __restrict__ off, int N, int* __restrict__ slot) {
    if (threadIdx.x == 0 && blockIdx.x == 0) slot[0] = off[N];  // # of type-0 edges
}

__global__ void k_scatter(const int* __restrict__ src, const int* __restrict__ dst,
                          const int* __restrict__ ety, int* __restrict__ cursor,
                          int* __restrict__ srcP, int* __restrict__ dstP, int M, int N) {
    int e = blockIdx.x * 256 + threadIdx.x;
    if (e < M) {
        int d = dst[e];
        int t = ety[e] & 1;
        int pos = atomicAdd(&cursor[t * N + d], 1);
        srcP[pos] = src[e] & 0x3FFFFFFF;
        dstP[pos] = d;
    }
}

// ---------- edge message MLP: one tile per wave, zero barriers ----------
__global__ __launch_bounds__(256, 2) void k_edge_mlp(
    const u16* __restrict__ hbf, const int* __restrict__ srcP, const int* __restrict__ dstP,
    const int* __restrict__ t0p, const float* __restrict__ w1, const float* __restrict__ b1,
    const float* __restrict__ w2, const float* __restrict__ b2,
    float* __restrict__ agg, int M) {
    __shared__ u16 sHid[4][4608];            // per-wave: hidden (stride 72) / msg (stride 70)
    __shared__ int sMS[4][64], sMD[4][64];   // per-wave meta

    const int tid = threadIdx.x;
    const int l = tid & 63, wv = tid >> 6;
    const int l15 = l & 15, quad = l >> 4;
    const f32x4 vz = {0.f, 0.f, 0.f, 0.f};

    const int T0 = *t0p;
    const int half = gridDim.x >> 1;
    const int ty = (blockIdx.x >= half) ? 1 : 0;
    const int bi = ty ? (int)blockIdx.x - half : (int)blockIdx.x;

    const int n_tiles = (M + 63) >> 6;
    const int tlo = ty ? (T0 >> 6) : 0;
    const int thi = ty ? n_tiles : ((T0 + 63) >> 6);
    const int lo = ty ? T0 : 0;
    const int hi = ty ? M : T0;
    const int range = thi - tlo;
    const int per = (range + half - 1) / half;
    const int c0 = tlo + bi * per;
    const int c1 = min(c0 + per, thi);

    // ---- register B fragments + biases for this block's type (static idx) ----
    short8 Bf1[4][4], Bf2[2][4];
    float b1r[4], b2r[4];
#pragma unroll
    for (int ni = 0; ni < 4; ++ni) {
        const int c = ni * 16 + l15;
        b1r[ni] = b1[ty * 64 + c];
        b2r[ni] = b2[ty * 64 + c];
#pragma unroll
        for (int s = 0; s < 4; ++s) {
            U8 tmp;
            const float* wp = w1 + (size_t)ty * 8192 + (size_t)(s * 32 + quad * 8) * 64 + c;
#pragma unroll
            for (int jp = 0; jp < 4; ++jp) tmp.u[jp] = pk(wp[(2 * jp) * 64], wp[(2 * jp + 1) * 64]);
            Bf1[s][ni] = tmp.v;
        }
#pragma unroll
        for (int s = 0; s < 2; ++s) {
            U8 tmp;
            const float* wp = w2 + (size_t)ty * 4096 + (size_t)(s * 32 + quad * 8) * 64 + c;
#pragma unroll
            for (int jp = 0; jp < 4; ++jp) tmp.u[jp] = pk(wp[(2 * jp) * 64], wp[(2 * jp + 1) * 64]);
            Bf2[s][ni] = tmp.v;
        }
    }

    u16* hid = sHid[wv];
    int* mS = sMS[wv];
    int* mD = sMD[wv];

    for (int tile = c0 + wv; tile < c1; tile += 4) {
        const int base = tile << 6;
        {   // meta (own wave's LDS only)
            int e = base + l;
            int ec = (e < M) ? e : (M - 1);
            mS[l] = srcP[ec];
            mD[l] = dstP[ec];
        }
        int rs[4], rd[4];
#pragma unroll
        for (int mi = 0; mi < 4; ++mi) {
            rs[mi] = mS[mi * 16 + l15];
            rd[mi] = mD[mi * 16 + l15];
        }
        short8 a1[4][4];
#pragma unroll
        for (int mi = 0; mi < 4; ++mi)
#pragma unroll
            for (int s = 0; s < 4; ++s) {
                const int row = (s < 2) ? rs[mi] : rd[mi];
                a1[mi][s] = *(const short8*)(hbf + (size_t)row * 64 + (s & 1) * 32 + quad * 8);
            }
        // ---- layer 1: hidden = relu(A @ W1 + b1) ----
#pragma unroll
        for (int mi = 0; mi < 4; ++mi) {
            f32x4 acc[4] = {vz, vz, vz, vz};
#pragma unroll
            for (int s = 0; s < 4; ++s)
#pragma unroll
                for (int ni = 0; ni < 4; ++ni)
                    acc[ni] = __builtin_amdgcn_mfma_f32_16x16x32_bf16(a1[mi][s], Bf1[s][ni], acc[ni], 0, 0, 0);
#pragma unroll
            for (int ni = 0; ni < 4; ++ni) {
                const int c = ni * 16 + l15;
#pragma unroll
                for (int r = 0; r < 4; ++r) {
                    float hv = fmaxf(acc[ni][r] + b1r[ni], 0.f);
                    hid[(mi * 16 + quad * 4 + r) * 72 + c] = (u16)f2bf(hv);
                }
            }
        }
        // ---- layer 2: msg = hidden @ W2 + b2 ----
        f32x4 acc2[4][4];
#pragma unroll
        for (int mi = 0; mi < 4; ++mi) {
            short8 a2a = *(const short8*)(hid + (mi * 16 + l15) * 72 + quad * 8);
            short8 a2b = *(const short8*)(hid + (mi * 16 + l15) * 72 + 32 + quad * 8);
#pragma unroll
            for (int ni = 0; ni < 4; ++ni) {
                f32x4 t = __builtin_amdgcn_mfma_f32_16x16x32_bf16(a2a, Bf2[0][ni], vz, 0, 0, 0);
                acc2[mi][ni] = __builtin_amdgcn_mfma_f32_16x16x32_bf16(a2b, Bf2[1][ni], t, 0, 0, 0);
            }
        }
        __asm__ volatile("s_waitcnt lgkmcnt(0)");  // hidden reads drained; reuse region for msg
#pragma unroll
        for (int mi = 0; mi < 4; ++mi)
#pragma unroll
            for (int ni = 0; ni < 4; ++ni) {
                const int c = ni * 16 + l15;
                const int e0 = mi * 16 + quad * 4;
                float bb = b2r[ni];
                *(u32*)(hid + c * 70 + e0) = pk(acc2[mi][ni][0] + bb, acc2[mi][ni][1] + bb);
                *(u32*)(hid + c * 70 + e0 + 2) = pk(acc2[mi][ni][2] + bb, acc2[mi][ni][3] + bb);
            }
        // ---- run-reduction (lane = column), 1 atomic per (run, col) ----
        {
            const int c = l;
            float a = 0.f;
            int cur = -1;
            for (int i = 0; i < 64; i += 2) {
                u32 pm = *(const u32*)(hid + c * 70 + i);
                int2 dd = *(const int2*)(mD + i);
                int eg = base + i;
                if (eg >= lo && eg < hi) {
                    if (dd.x != cur) {
                        if (cur >= 0) unsafeAtomicAdd(agg + (size_t)cur * 64 + c, a);
                        cur = dd.x; a = 0.f;
                    }
                    a += bflo(pm);
                }
                if (eg + 1 >= lo && eg + 1 < hi) {
                    if (dd.y != cur) {
                        if (cur >= 0) unsafeAtomicAdd(agg + (size_t)cur * 64 + c, a);
                        cur = dd.y; a = 0.f;
                    }
                    a += bfhi(pm);
                }
            }
            if (cur >= 0) unsafeAtomicAdd(agg + (size_t)cur * 64 + c, a);
        }
    }
}

// ---------- GRU via MFMA: one 16-node tile per wave, zero steady-state barriers ----------
// Output cols 0..255 = [r(64) | z(64) | i_n(64) | h_n(64)]. Weights staged once
// into LDS (col-major, k-contiguous, bf16); A built from global (agg fp32->bf16,
// h from hbf). D-layout keeps all 4 gates of (node, j) in one lane -> in-register
// GRU combine, direct stores to h/hbf.
__global__ __launch_bounds__(256, 2) void k_gru_gemm(
    const float* __restrict__ agg, float* __restrict__ h, u16* __restrict__ hbf,
    const float* __restrict__ wi, const float* __restrict__ wh,
    const float* __restrict__ bi, const float* __restrict__ bh, int n_nodes) {
    __shared__ u16 sRZ[128 * 136];  // cols 0..127 (r|z), K=128 = [agg|h], stride 136
    __shared__ u16 sIN[64 * 72];    // i_n cols, K=64 (agg)
    __shared__ u16 sHN[64 * 72];    // h_n cols, K=64 (h)

    const int tid = threadIdx.x;
    const int l = tid & 63, wv = tid >> 6;
    const int l15 = l & 15, quad = l >> 4;
    const f32x4 vz = {0.f, 0.f, 0.f, 0.f};

    // stage weights (bf16) once
    for (int u = tid; u < 128 * 64; u += 256) {
        int c = u >> 6, k0 = (u & 63) * 2;
        float v0 = (k0 < 64) ? wi[k0 * 192 + c] : wh[(k0 - 64) * 192 + c];
        float v1 = (k0 < 64) ? wi[(k0 + 1) * 192 + c] : wh[(k0 + 1 - 64) * 192 + c];
        *(u32*)(sRZ + c * 136 + k0) = pk(v0, v1);
    }
    for (int u = tid; u < 64 * 32; u += 256) {
        int c = u >> 5, k0 = (u & 31) * 2;
        *(u32*)(sIN + c * 72 + k0) = pk(wi[k0 * 192 + 128 + c], wi[(k0 + 1) * 192 + 128 + c]);
        *(u32*)(sHN + c * 72 + k0) = pk(wh[k0 * 192 + 128 + c], wh[(k0 + 1) * 192 + 128 + c]);
    }
    // per-lane biases: j = nt*16 + l15 within each gate
    float bR[4], bZ[4], bI[4], bH[4];
#pragma unroll
    for (int nt = 0; nt < 4; ++nt) {
        int j = nt * 16 + l15;
        bR[nt] = bi[j] + bh[j];
        bZ[nt] = bi[64 + j] + bh[64 + j];
        bI[nt] = bi[128 + j];
        bH[nt] = bh[128 + j];
    }
    __syncthreads();  // the only barrier

    const int n_tiles = (n_nodes + 15) >> 4;
    for (int tile = blockIdx.x * 4 + wv; tile < n_tiles; tile += gridDim.x * 4) {
        const int nb = tile << 4;
        const int arow = nb + l15;
        const int rowc = (arow < n_nodes) ? arow : (n_nodes - 1);
        // A fragments: agg (fp32 -> bf16 pack) and h (hbf direct)
        short8 aA[2], aH[2];
#pragma unroll
        for (int s = 0; s < 2; ++s) {
            const float* ap = agg + (size_t)rowc * 64 + s * 32 + quad * 8;
            U8 t;
#pragma unroll
            for (int jp = 0; jp < 4; ++jp) t.u[jp] = pk(ap[2 * jp], ap[2 * jp + 1]);
            aA[s] = t.v;
            aH[s] = *(const short8*)(hbf + (size_t)rowc * 64 + s * 32 + quad * 8);
        }
        f32x4 D[16];
#pragma unroll
        for (int i = 0; i < 16; ++i) D[i] = vz;
#pragma unroll
        for (int nt = 0; nt < 8; ++nt) {
            const u16* bp = sRZ + (nt * 16 + l15) * 136 + quad * 8;
            D[nt] = __builtin_amdgcn_mfma_f32_16x16x32_bf16(aA[0], *(const short8*)bp, D[nt], 0, 0, 0);
            D[nt] = __builtin_amdgcn_mfma_f32_16x16x32_bf16(aA[1], *(const short8*)(bp + 32), D[nt], 0, 0, 0);
            D[nt] = __builtin_amdgcn_mfma_f32_16x16x32_bf16(aH[0], *(const short8*)(bp + 64), D[nt], 0, 0, 0);
            D[nt] = __builtin_amdgcn_mfma_f32_16x16x32_bf16(aH[1], *(const short8*)(bp + 96), D[nt], 0, 0, 0);
        }
#pragma unroll
        for (int nt = 0; nt < 4; ++nt) {
            const u16* ip = sIN + (nt * 16 + l15) * 72 + quad * 8;
            D[8 + nt] = __builtin_amdgcn_mfma_f32_16x16x32_bf16(aA[0], *(const short8*)ip, D[8 + nt], 0, 0, 0);
            D[8 + nt] = __builtin_amdgcn_mfma_f32_16x16x32_bf16(aA[1], *(const short8*)(ip + 32), D[8 + nt], 0, 0, 0);
            const u16* hp = sHN + (nt * 16 + l15) * 72 + quad * 8;
            D[12 + nt] = __builtin_amdgcn_mfma_f32_16x16x32_bf16(aH[0], *(const short8*)hp, D[12 + nt], 0, 0, 0);
            D[12 + nt] = __builtin_amdgcn_mfma_f32_16x16x32_bf16(aH[1], *(const short8*)(hp + 32), D[12 + nt], 0, 0, 0);
        }
        // in-register GRU combine: lane owns nodes nb+quad*4+{0..3}, cols nt*16+l15
#pragma unroll
        for (int nt = 0; nt < 4; ++nt) {
            const int j = nt * 16 + l15;
#pragma unroll
            for (int r = 0; r < 4; ++r) {
                const int nd = nb + quad * 4 + r;
                if (nd < n_nodes) {
                    float rsv = D[nt][r] + bR[nt];
                    float zsv = D[4 + nt][r] + bZ[nt];
                    float inv = D[8 + nt][r] + bI[nt];
                    float hnv = D[12 + nt][r] + bH[nt];
                    float rr = 1.f / (1.f + __expf(-rsv));
                    float zz = 1.f / (1.f + __expf(-zsv));
                    float nn = tanhf(fmaf(rr, hnv, inv));
                    float hv = h[(size_t)nd * 64 + j];
                    float nh = (1.f - zz) * nn + zz * hv;
                    h[(size_t)nd * 64 + j] = nh;
                    hbf[(size_t)nd * 64 + j] = (u16)f2bf(nh);
                }
            }
        }
    }
}

// ---------- readout + data-qubit correction (wave per node) ----------
__global__ void k_readout(const float* __restrict__ h, const float* __restrict__ x,
                          const int* __restrict__ node_type, const float* __restrict__ w1,
                          const float* __restrict__ b1, const float* __restrict__ w2,
                          const float* __restrict__ b2, float* __restrict__ out, int n_nodes) {
    const int lane = threadIdx.x & 63;
    const int node = blockIdx.x * 4 + (threadIdx.x >> 6);
    if (node >= n_nodes) return;
    float hv = h[(size_t)node * 64 + lane];
    float acc = b1[lane];
    for (int k = 0; k < 64; ++k) acc = fmaf(__shfl(hv, k), w1[k * 64 + lane], acc);
    float t = fmaxf(acc, 0.f) * w2[lane];
#pragma unroll
    for (int off = 32; off > 0; off >>= 1) t += __shfl_xor(t, off);
    if (lane == 0) {
        float o = t + b2[0];
        out[node] = (node_type[node] == 0) ? (x[node * 4] + o) : 0.f;
    }
}

extern "C" void kernel_launch(void* const* d_in, const int* in_sizes, int n_in, void* d_out,
                              int out_size, void* d_ws, size_t ws_size, hipStream_t stream) {
    const float* x = (const float*)d_in[0];
    const int* node_type = (const int*)d_in[1];
    const int* edge_index = (const int*)d_in[2];
    const int* edge_type = (const int*)d_in[3];
    const float* in_w = (const float*)d_in[4];
    const float* in_b = (const float*)d_in[5];
    const float* ln_g = (const float*)d_in[6];
    const float* ln_b = (const float*)d_in[7];
    const float* mlp_w1 = (const float*)d_in[8];
    const float* mlp_b1 = (const float*)d_in[9];
    const float* mlp_w2 = (const float*)d_in[10];
    const float* mlp_b2 = (const float*)d_in[11];
    const float* gru_wi = (const float*)d_in[12];
    const float* gru_wh = (const float*)d_in[13];
    const float* gru_bi = (const float*)d_in[14];
    const float* gru_bh = (const float*)d_in[15];
    const float* ro_w1 = (const float*)d_in[16];
    const float* ro_b1 = (const float*)d_in[17];
    const float* ro_w2 = (const float*)d_in[18];
    const float* ro_b2 = (const float*)d_in[19];

    const int N = in_sizes[1];  // nodes
    const int M = in_sizes[3];  // edges
    const int* src = edge_index;
    const int* dst = edge_index + M;

    // ws: h (N*256B) | agg (N*256B) | hbf (N*128B) | off (2N*4) | part (4KB) | srcP | dstP
    char* wsb = (char*)d_ws;
    float* h = (float*)wsb;
    float* agg = (float*)(wsb + (size_t)N * 256);
    u16* hbf = (u16*)(wsb + (size_t)N * 512);
    int* off = (int*)(wsb + (size_t)N * 640);
    int* part = (int*)(wsb + (size_t)N * 640 + (size_t)2 * N * 4);
    int* srcP = (int*)(wsb + (size_t)N * 640 + (size_t)2 * N * 4 + 4096);
    int* dstP = srcP + M;
    int* t0slot = part + 1000;

    const int NB = 2 * N;
    const int nb = (NB + 1023) / 1024;

    // build (type,dst)-sorted edge permutation (reused by all 3 layers)
    hipMemsetAsync(off, 0, (size_t)NB * sizeof(int), stream);
    k_hist<<<(M + 255) / 256, 256, 0, stream>>>(dst, edge_type, off, M, N);
    k_scan1<<<nb, 1024, 0, stream>>>(off, part, NB);
    k_scan2<<<1, 64, 0, stream>>>(part, nb);
    k_scan3<<<nb, 1024, 0, stream>>>(off, part, NB);
    k_savet0<<<1, 64, 0, stream>>>(off, N, t0slot);
    k_scatter<<<(M + 255) / 256, 256, 0, stream>>>(src, dst, edge_type, off, srcP, dstP, M, N);

    k_input_proj<<<(N + 3) / 4, 256, 0, stream>>>(x, in_w, in_b, ln_g, ln_b, h, hbf, N);
    for (int l = 0; l < 3; ++l) {
        hipMemsetAsync(agg, 0, (size_t)N * 64 * sizeof(float), stream);
        k_edge_mlp<<<1024, 256, 0, stream>>>(hbf, srcP, dstP, t0slot,
                                             mlp_w1 + (size_t)l * 2 * 128 * 64,
                                             mlp_b1 + (size_t)l * 2 * 64,
                                             mlp_w2 + (size_t)l * 2 * 64 * 64,
                                             mlp_b2 + (size_t)l * 2 * 64, agg, M);
        k_gru_gemm<<<512, 256, 0, stream>>>(agg, h, hbf, gru_wi + (size_t)l * 64 * 192,
                                            gru_wh + (size_t)l * 64 * 192,
                                            gru_bi + (size_t)l * 192, gru_bh + (size_t)l * 192, N);
    }
    k_readout<<<(N + 3) / 4, 256, 0, stream>>>(h, x, node_type, ro_w1, ro_b1, ro_w2, ro_b2,
                                               (float*)d_out, N);
}

// Round 6
// 1086.991 us; speedup vs baseline: 6.8490x; 1.0086x over previous
//
#include <hip/hip_runtime.h>

typedef unsigned int u32;
typedef unsigned short u16;
typedef unsigned long long u64;

using short8 = __attribute__((ext_vector_type(8))) short;
using f32x4  = __attribute__((ext_vector_type(4))) float;

// ---------- bf16 helpers ----------
__device__ __forceinline__ u32 f2bf(float f) {  // RTN-even (weights/A staging)
    u32 u = __float_as_uint(f);
    return (u + 0x7fffu + ((u >> 16) & 1u)) >> 16;
}
__device__ __forceinline__ u32 pk(float a, float b) {
    return f2bf(a) | (f2bf(b) << 16);
}
__device__ __forceinline__ u32 f2bf_fast(float f) {  // round-half-up, 2 inst
    return (__float_as_uint(f) + 0x8000u) >> 16;
}
__device__ __forceinline__ u32 pk_fast(float a, float b) {
    return f2bf_fast(a) | (f2bf_fast(b) << 16);
}
__device__ __forceinline__ float bflo(u32 u) { return __uint_as_float(u << 16); }
__device__ __forceinline__ float bfhi(u32 u) { return __uint_as_float(u & 0xffff0000u); }

union U8 { u32 u[4]; short8 v; };

// ---------- input projection + LayerNorm + ReLU (wave per node) ----------
__global__ void k_input_proj(const float* __restrict__ x, const float* __restrict__ in_w,
                             const float* __restrict__ in_b, const float* __restrict__ ln_g,
                             const float* __restrict__ ln_b, float* __restrict__ h,
                             u16* __restrict__ hbf, int n_nodes) {
    const int lane = threadIdx.x & 63;
    const int node = blockIdx.x * 4 + (threadIdx.x >> 6);
    if (node >= n_nodes) return;
    float acc = in_b[lane];
#pragma unroll
    for (int k = 0; k < 4; ++k) acc = fmaf(x[node * 4 + k], in_w[k * 64 + lane], acc);
    float s = acc;
#pragma unroll
    for (int off = 32; off > 0; off >>= 1) s += __shfl_xor(s, off);
    float mu = s * (1.f / 64.f);
    float d = acc - mu;
    float vs = d * d;
#pragma unroll
    for (int off = 32; off > 0; off >>= 1) vs += __shfl_xor(vs, off);
    float inv = rsqrtf(vs * (1.f / 64.f) + 1e-5f);
    float hv = fmaxf(d * inv * ln_g[lane] + ln_b[lane], 0.f);
    h[(size_t)node * 64 + lane] = hv;
    hbf[(size_t)node * 64 + lane] = (u16)f2bf(hv);
}

// ---------- (type,dst)-sort: histogram, scan, scatter ----------
__global__ void k_hist(const int* __restrict__ dst, const int* __restrict__ ety,
                       int* __restrict__ cnt, int M, int N) {
    int i = blockIdx.x * 256 + threadIdx.x;
    if (i < M) atomicAdd(&cnt[(ety[i] & 1) * N + dst[i]], 1);
}

__global__ void k_scan1(int* __restrict__ data, int* __restrict__ part, int N) {
    __shared__ int s[1024];
    const int t = threadIdx.x;
    const int i = blockIdx.x * 1024 + t;
    int v = (i < N) ? data[i] : 0;
    s[t] = v;
    __syncthreads();
#pragma unroll
    for (int d = 1; d < 1024; d <<= 1) {
        int x = (t >= d) ? s[t - d] : 0;
        __syncthreads();
        s[t] += x;
        __syncthreads();
    }
    if (i < N) data[i] = s[t] - v;  // exclusive
    if (t == 1023) part[blockIdx.x] = s[1023];
}

__global__ void k_scan2(int* __restrict__ part, int nb) {
    if (threadIdx.x == 0 && blockIdx.x == 0) {
        int a = 0;
        for (int i = 0; i < nb; ++i) { int t = part[i]; part[i] = a; a += t; }
    }
}

__global__ void k_scan3(int* __restrict__ data, const int* __restrict__ part, int N,
                        int saveIdx, int* __restrict__ slot) {
    int i = blockIdx.x * 1024 + threadIdx.x;
    if (i < N) {
        int v = data[i] + part[blockIdx.x];
        data[i] = v;
        if (i == saveIdx) slot[0] = v;  // T0 = # of type-0 edges
    }
}

__global__ void k_scatter(const int* __restrict__ src, const int* __restrict__ dst,
                          const int* __restrict__ ety, int* __restrict__ cursor,
                          int* __restrict__ srcP, int* __restrict__ dstP, int M, int N) {
    int e = blockIdx.x * 256 + threadIdx.x;
    if (e < M) {
        int d = dst[e];
        int t = ety[e] & 1;
        int pos = atomicAdd(&cursor[t * N + d], 1);
        srcP[pos] = src[e] & 0x3FFFFFFF;
        dstP[pos] = d;
    }
}

// ---------- edge message MLP: one tile per wave, zero barriers, 1-deep pipeline ----------
// Edges sorted by (type,dst); type is block-static (W1/W2 fragments in registers).
// Meta lives in registers (rows broadcast via __shfl / ds_bpermute). A-gathers for
// tile t+1 are issued right after layer-1 of tile t consumes the a1 regs, hiding
// gather latency behind layer-2 + epilogue. Run-reduction is driven by a ballot
// mask in SGPRs with scalar branch-outs (one atomic instr per run, 64 cols wide).
__global__ __launch_bounds__(256, 2) void k_edge_mlp(
    const u16* __restrict__ hbf, const int* __restrict__ srcP, const int* __restrict__ dstP,
    const int* __restrict__ t0p, const float* __restrict__ w1, const float* __restrict__ b1,
    const float* __restrict__ w2, const float* __restrict__ b2,
    float* __restrict__ agg, int M) {
    __shared__ u16 sHid[4][4608];   // per-wave hidden [row][col] stride 72
    __shared__ u16 sMsg[4][4864];   // per-wave msg    [col][edge] stride 76 (disjoint)

    const int tid = threadIdx.x;
    const int l = tid & 63, wv = tid >> 6;
    const int l15 = l & 15, quad = l >> 4;
    const f32x4 vz = {0.f, 0.f, 0.f, 0.f};

    const int T0 = *t0p;
    const int half = gridDim.x >> 1;
    const int ty = (blockIdx.x >= half) ? 1 : 0;
    const int bi = ty ? (int)blockIdx.x - half : (int)blockIdx.x;

    const int n_tiles = (M + 63) >> 6;
    const int tlo = ty ? (T0 >> 6) : 0;
    const int thi = ty ? n_tiles : ((T0 + 63) >> 6);
    const int lo = ty ? T0 : 0;
    const int hi = ty ? M : T0;
    const int range = thi - tlo;
    const int per = (range + half - 1) / half;
    const int c0 = tlo + bi * per;
    const int c1 = min(c0 + per, thi);

    // ---- register B fragments + biases for this block's type (static idx) ----
    short8 Bf1[4][4], Bf2[2][4];
    float b1r[4], b2r[4];
#pragma unroll
    for (int ni = 0; ni < 4; ++ni) {
        const int c = ni * 16 + l15;
        b1r[ni] = b1[ty * 64 + c];
        b2r[ni] = b2[ty * 64 + c];
#pragma unroll
        for (int s = 0; s < 4; ++s) {
            U8 tmp;
            const float* wp = w1 + (size_t)ty * 8192 + (size_t)(s * 32 + quad * 8) * 64 + c;
#pragma unroll
            for (int jp = 0; jp < 4; ++jp) tmp.u[jp] = pk(wp[(2 * jp) * 64], wp[(2 * jp + 1) * 64]);
            Bf1[s][ni] = tmp.v;
        }
#pragma unroll
        for (int s = 0; s < 2; ++s) {
            U8 tmp;
            const float* wp = w2 + (size_t)ty * 4096 + (size_t)(s * 32 + quad * 8) * 64 + c;
#pragma unroll
            for (int jp = 0; jp < 4; ++jp) tmp.u[jp] = pk(wp[(2 * jp) * 64], wp[(2 * jp + 1) * 64]);
            Bf2[s][ni] = tmp.v;
        }
    }

    u16* hid = sHid[wv];
    u16* msg = sMsg[wv];

    int t = c0 + wv;
    int mdr_c = -1;      // current tile: this lane's edge dst
    int rs[4], rd[4];
    short8 a1[4][4];
    if (t < c1) {        // prologue: meta + A loads for first tile
        int e = (t << 6) + l;
        int ec = min(e, M - 1);
        int ms = srcP[ec];
        mdr_c = dstP[ec];
#pragma unroll
        for (int mi = 0; mi < 4; ++mi) {
            rs[mi] = __shfl(ms, mi * 16 + l15);
            rd[mi] = __shfl(mdr_c, mi * 16 + l15);
        }
#pragma unroll
        for (int mi = 0; mi < 4; ++mi)
#pragma unroll
            for (int s = 0; s < 4; ++s) {
                const int row = (s < 2) ? rs[mi] : rd[mi];
                a1[mi][s] = *(const short8*)(hbf + (size_t)row * 64 + (s & 1) * 32 + quad * 8);
            }
    }

    for (; t < c1; t += 4) {
        const int base = t << 6;
        // prefetch next tile's meta (clamped; harmless past end)
        const int ecn = min(((t + 4) << 6) + l, M - 1);
        int msr_n = srcP[ecn];
        int mdr_n = dstP[ecn];

        // ---- layer 1: hidden = relu(A @ W1 + b1) ----
#pragma unroll
        for (int mi = 0; mi < 4; ++mi) {
            f32x4 acc[4] = {vz, vz, vz, vz};
#pragma unroll
            for (int s = 0; s < 4; ++s)
#pragma unroll
                for (int ni = 0; ni < 4; ++ni)
                    acc[ni] = __builtin_amdgcn_mfma_f32_16x16x32_bf16(a1[mi][s], Bf1[s][ni], acc[ni], 0, 0, 0);
#pragma unroll
            for (int ni = 0; ni < 4; ++ni) {
                const int c = ni * 16 + l15;
#pragma unroll
                for (int r = 0; r < 4; ++r) {
                    float hv = fmaxf(acc[ni][r] + b1r[ni], 0.f);
                    hid[(mi * 16 + quad * 4 + r) * 72 + c] = (u16)f2bf_fast(hv);
                }
            }
        }

        // ---- issue next tile's A-gathers into the (now dead) a1 regs ----
#pragma unroll
        for (int mi = 0; mi < 4; ++mi) {
            rs[mi] = __shfl(msr_n, mi * 16 + l15);
            rd[mi] = __shfl(mdr_n, mi * 16 + l15);
        }
#pragma unroll
        for (int mi = 0; mi < 4; ++mi)
#pragma unroll
            for (int s = 0; s < 4; ++s) {
                const int row = (s < 2) ? rs[mi] : rd[mi];
                a1[mi][s] = *(const short8*)(hbf + (size_t)row * 64 + (s & 1) * 32 + quad * 8);
            }

        // ---- layer 2: msg = hidden @ W2 + b2 (per-mi, write immediately) ----
#pragma unroll
        for (int mi = 0; mi < 4; ++mi) {
            short8 a2a = *(const short8*)(hid + (mi * 16 + l15) * 72 + quad * 8);
            short8 a2b = *(const short8*)(hid + (mi * 16 + l15) * 72 + 32 + quad * 8);
#pragma unroll
            for (int ni = 0; ni < 4; ++ni) {
                f32x4 tt = __builtin_amdgcn_mfma_f32_16x16x32_bf16(a2a, Bf2[0][ni], vz, 0, 0, 0);
                f32x4 m2 = __builtin_amdgcn_mfma_f32_16x16x32_bf16(a2b, Bf2[1][ni], tt, 0, 0, 0);
                const int c = ni * 16 + l15;
                const int e0 = mi * 16 + quad * 4;
                const float bb = b2r[ni];
                *(u32*)(msg + c * 76 + e0) = pk_fast(m2[0] + bb, m2[1] + bb);
                *(u32*)(msg + c * 76 + e0 + 2) = pk_fast(m2[2] + bb, m2[3] + bb);
            }
        }

        // ---- run-reduction: ballot mask in SGPRs, scalar branch per run-end ----
        {
            int eg = base + l;
            int dvz = (eg >= lo && eg < hi) ? mdr_c : -1;     // invalid edges -> dst=-1 runs
            int dprev = __shfl_up(dvz, 1);
            u64 mask = __ballot((l == 0) || (dvz != dprev));  // bit e = run start
            float a = 0.f;
#pragma unroll
            for (int i = 0; i < 64; i += 4) {
                uint2 pr = *(const uint2*)(msg + l * 76 + i);
                float v0 = bflo(pr.x), v1 = bfhi(pr.x), v2 = bflo(pr.y), v3 = bfhi(pr.y);
#define RR_STEP(ii, vv)                                                         \
                a += (vv);                                                      \
                if ((ii) == 63 || ((mask >> ((ii) + 1)) & 1ull)) {              \
                    int dd = __builtin_amdgcn_readlane(dvz, (ii));              \
                    if (dd >= 0) unsafeAtomicAdd(agg + (size_t)dd * 64 + l, a); \
                    a = 0.f;                                                    \
                }
                RR_STEP(i, v0)
                RR_STEP(i + 1, v1)
                RR_STEP(i + 2, v2)
                RR_STEP(i + 3, v3)
#undef RR_STEP
            }
        }
        mdr_c = mdr_n;  // rotate
    }
}

// ---------- GRU via MFMA: one 16-node tile per wave; fused combine + agg re-zero ----------
__global__ __launch_bounds__(256, 3) void k_gru_gemm(
    const float* __restrict__ agg, float* __restrict__ h, u16* __restrict__ hbf,
    const float* __restrict__ wi, const float* __restrict__ wh,
    const float* __restrict__ bi, const float* __restrict__ bh, int n_nodes) {
    extern __shared__ u16 smem[];
    u16* sRZ = smem;                 // 128 cols x stride 136 (r|z), K=128=[agg|h]
    u16* sIN = smem + 128 * 136;     // 64 cols x stride 72, K=64 (agg)
    u16* sHN = sIN + 64 * 72;        // 64 cols x stride 72, K=64 (h)

    const int tid = threadIdx.x;
    const int l = tid & 63, wv = tid >> 6;
    const int l15 = l & 15, quad = l >> 4;
    const f32x4 vz = {0.f, 0.f, 0.f, 0.f};

    for (int u = tid; u < 128 * 64; u += 256) {
        int c = u >> 6, k0 = (u & 63) * 2;
        float v0 = (k0 < 64) ? wi[k0 * 192 + c] : wh[(k0 - 64) * 192 + c];
        float v1 = (k0 < 64) ? wi[(k0 + 1) * 192 + c] : wh[(k0 + 1 - 64) * 192 + c];
        *(u32*)(sRZ + c * 136 + k0) = pk(v0, v1);
    }
    for (int u = tid; u < 64 * 32; u += 256) {
        int c = u >> 5, k0 = (u & 31) * 2;
        *(u32*)(sIN + c * 72 + k0) = pk(wi[k0 * 192 + 128 + c], wi[(k0 + 1) * 192 + 128 + c]);
        *(u32*)(sHN + c * 72 + k0) = pk(wh[k0 * 192 + 128 + c], wh[(k0 + 1) * 192 + 128 + c]);
    }
    float bR[4], bZ[4], bI[4], bH[4];
#pragma unroll
    for (int nt = 0; nt < 4; ++nt) {
        int j = nt * 16 + l15;
        bR[nt] = bi[j] + bh[j];
        bZ[nt] = bi[64 + j] + bh[64 + j];
        bI[nt] = bi[128 + j];
        bH[nt] = bh[128 + j];
    }
    __syncthreads();  // the only barrier

    const f32x4 z4 = {0.f, 0.f, 0.f, 0.f};
    const int n_tiles = (n_nodes + 15) >> 4;
    for (int tile = blockIdx.x * 4 + wv; tile < n_tiles; tile += gridDim.x * 4) {
        const int nb = tile << 4;
        const int arow = nb + l15;
        const int rowc = (arow < n_nodes) ? arow : (n_nodes - 1);
        short8 aA[2], aH[2];
#pragma unroll
        for (int s = 0; s < 2; ++s) {
            const float* ap = agg + (size_t)rowc * 64 + s * 32 + quad * 8;
            U8 tt;
#pragma unroll
            for (int jp = 0; jp < 4; ++jp) tt.u[jp] = pk(ap[2 * jp], ap[2 * jp + 1]);
            aA[s] = tt.v;
            aH[s] = *(const short8*)(hbf + (size_t)rowc * 64 + s * 32 + quad * 8);
        }
        // re-zero agg for the next layer (this tile's rows are exclusively ours)
        if (arow < n_nodes) {
#pragma unroll
            for (int s = 0; s < 2; ++s) {
                *(f32x4*)(agg + (size_t)rowc * 64 + s * 32 + quad * 8) = z4;
                *(f32x4*)(agg + (size_t)rowc * 64 + s * 32 + quad * 8 + 4) = z4;
            }
        }
        f32x4 D[16];
#pragma unroll
        for (int i = 0; i < 16; ++i) D[i] = vz;
#pragma unroll
        for (int nt = 0; nt < 8; ++nt) {
            const u16* bp = sRZ + (nt * 16 + l15) * 136 + quad * 8;
            D[nt] = __builtin_amdgcn_mfma_f32_16x16x32_bf16(aA[0], *(const short8*)bp, D[nt], 0, 0, 0);
            D[nt] = __builtin_amdgcn_mfma_f32_16x16x32_bf16(aA[1], *(const short8*)(bp + 32), D[nt], 0, 0, 0);
            D[nt] = __builtin_amdgcn_mfma_f32_16x16x32_bf16(aH[0], *(const short8*)(bp + 64), D[nt], 0, 0, 0);
            D[nt] = __builtin_amdgcn_mfma_f32_16x16x32_bf16(aH[1], *(const short8*)(bp + 96), D[nt], 0, 0, 0);
        }
#pragma unroll
        for (int nt = 0; nt < 4; ++nt) {
            const u16* ip = sIN + (nt * 16 + l15) * 72 + quad * 8;
            D[8 + nt] = __builtin_amdgcn_mfma_f32_16x16x32_bf16(aA[0], *(const short8*)ip, D[8 + nt], 0, 0, 0);
            D[8 + nt] = __builtin_amdgcn_mfma_f32_16x16x32_bf16(aA[1], *(const short8*)(ip + 32), D[8 + nt], 0, 0, 0);
            const u16* hp = sHN + (nt * 16 + l15) * 72 + quad * 8;
            D[12 + nt] = __builtin_amdgcn_mfma_f32_16x16x32_bf16(aH[0], *(const short8*)hp, D[12 + nt], 0, 0, 0);
            D[12 + nt] = __builtin_amdgcn_mfma_f32_16x16x32_bf16(aH[1], *(const short8*)(hp + 32), D[12 + nt], 0, 0, 0);
        }
#pragma unroll
        for (int nt = 0; nt < 4; ++nt) {
            const int j = nt * 16 + l15;
#pragma unroll
            for (int r = 0; r < 4; ++r) {
                const int nd = nb + quad * 4 + r;
                if (nd < n_nodes) {
                    float rsv = D[nt][r] + bR[nt];
                    float zsv = D[4 + nt][r] + bZ[nt];
                    float inv = D[8 + nt][r] + bI[nt];
                    float hnv = D[12 + nt][r] + bH[nt];
                    float rr = 1.f / (1.f + __expf(-rsv));
                    float zz = 1.f / (1.f + __expf(-zsv));
                    float nn = tanhf(fmaf(rr, hnv, inv));
                    float hv = h[(size_t)nd * 64 + j];
                    float nh = (1.f - zz) * nn + zz * hv;
                    h[(size_t)nd * 64 + j] = nh;
                    hbf[(size_t)nd * 64 + j] = (u16)f2bf(nh);
                }
            }
        }
    }
}

// ---------- readout + data-qubit correction (wave per node) ----------
__global__ void k_readout(const float* __restrict__ h, const float* __restrict__ x,
                          const int* __restrict__ node_type, const float* __restrict__ w1,
                          const float* __restrict__ b1, const float* __restrict__ w2,
                          const float* __restrict__ b2, float* __restrict__ out, int n_nodes) {
    const int lane = threadIdx.x & 63;
    const int node = blockIdx.x * 4 + (threadIdx.x >> 6);
    if (node >= n_nodes) return;
    float hv = h[(size_t)node * 64 + lane];
    float acc = b1[lane];
    for (int k = 0; k < 64; ++k) acc = fmaf(__shfl(hv, k), w1[k * 64 + lane], acc);
    float t = fmaxf(acc, 0.f) * w2[lane];
#pragma unroll
    for (int off = 32; off > 0; off >>= 1) t += __shfl_xor(t, off);
    if (lane == 0) {
        float o = t + b2[0];
        out[node] = (node_type[node] == 0) ? (x[node * 4] + o) : 0.f;
    }
}

extern "C" void kernel_launch(void* const* d_in, const int* in_sizes, int n_in, void* d_out,
                              int out_size, void* d_ws, size_t ws_size, hipStream_t stream) {
    const float* x = (const float*)d_in[0];
    const int* node_type = (const int*)d_in[1];
    const int* edge_index = (const int*)d_in[2];
    const int* edge_type = (const int*)d_in[3];
    const float* in_w = (const float*)d_in[4];
    const float* in_b = (const float*)d_in[5];
    const float* ln_g = (const float*)d_in[6];
    const float* ln_b = (const float*)d_in[7];
    const float* mlp_w1 = (const float*)d_in[8];
    const float* mlp_b1 = (const float*)d_in[9];
    const float* mlp_w2 = (const float*)d_in[10];
    const float* mlp_b2 = (const float*)d_in[11];
    const float* gru_wi = (const float*)d_in[12];
    const float* gru_wh = (const float*)d_in[13];
    const float* gru_bi = (const float*)d_in[14];
    const float* gru_bh = (const float*)d_in[15];
    const float* ro_w1 = (const float*)d_in[16];
    const float* ro_b1 = (const float*)d_in[17];
    const float* ro_w2 = (const float*)d_in[18];
    const float* ro_b2 = (const float*)d_in[19];

    const int N = in_sizes[1];  // nodes
    const int M = in_sizes[3];  // edges
    const int* src = edge_index;
    const int* dst = edge_index + M;

    // ws: h (N*256B) | agg (N*256B) | hbf (N*128B) | off (2N*4) | part (4KB) | srcP | dstP
    char* wsb = (char*)d_ws;
    float* h = (float*)wsb;
    float* agg = (float*)(wsb + (size_t)N * 256);
    u16* hbf = (u16*)(wsb + (size_t)N * 512);
    int* off = (int*)(wsb + (size_t)N * 640);
    int* part = (int*)(wsb + (size_t)N * 640 + (size_t)2 * N * 4);
    int* srcP = (int*)(wsb + (size_t)N * 640 + (size_t)2 * N * 4 + 4096);
    int* dstP = srcP + M;
    int* t0slot = part + 1000;

    const int NB = 2 * N;
    const int nb = (NB + 1023) / 1024;

    // build (type,dst)-sorted edge permutation (reused by all 3 layers)
    hipMemsetAsync(off, 0, (size_t)NB * sizeof(int), stream);
    k_hist<<<(M + 255) / 256, 256, 0, stream>>>(dst, edge_type, off, M, N);
    k_scan1<<<nb, 1024, 0, stream>>>(off, part, NB);
    k_scan2<<<1, 64, 0, stream>>>(part, nb);
    k_scan3<<<nb, 1024, 0, stream>>>(off, part, NB, N, t0slot);
    k_scatter<<<(M + 255) / 256, 256, 0, stream>>>(src, dst, edge_type, off, srcP, dstP, M, N);

    k_input_proj<<<(N + 3) / 4, 256, 0, stream>>>(x, in_w, in_b, ln_g, ln_b, h, hbf, N);
    hipMemsetAsync(agg, 0, (size_t)N * 64 * sizeof(float), stream);  // layer 0 only; GRU re-zeros
    const size_t gruLds = (size_t)(128 * 136 + 64 * 72 + 64 * 72) * sizeof(u16);  // 53248
    for (int l = 0; l < 3; ++l) {
        k_edge_mlp<<<1024, 256, 0, stream>>>(hbf, srcP, dstP, t0slot,
                                             mlp_w1 + (size_t)l * 2 * 128 * 64,
                                             mlp_b1 + (size_t)l * 2 * 64,
                                             mlp_w2 + (size_t)l * 2 * 64 * 64,
                                             mlp_b2 + (size_t)l * 2 * 64, agg, M);
        k_gru_gemm<<<512, 256, gruLds, stream>>>(agg, h, hbf, gru_wi + (size_t)l * 64 * 192,
                                                 gru_wh + (size_t)l * 64 * 192,
                                                 gru_bi + (size_t)l * 192, gru_bh + (size_t)l * 192, N);
    }
    k_readout<<<(N + 3) / 4, 256, 0, stream>>>(h, x, node_type, ro_w1, ro_b1, ro_w2, ro_b2,
                                               (float*)d_out, N);
}

// Round 7
// 1079.209 us; speedup vs baseline: 6.8984x; 1.0072x over previous
//
#include <hip/hip_runtime.h>

typedef unsigned int u32;
typedef unsigned short u16;
typedef unsigned long long u64;

using short8 = __attribute__((ext_vector_type(8))) short;
using f32x4  = __attribute__((ext_vector_type(4))) float;

// ---------- bf16 helpers ----------
__device__ __forceinline__ u32 f2bf(float f) {  // RTN-even (weights/A staging)
    u32 u = __float_as_uint(f);
    return (u + 0x7fffu + ((u >> 16) & 1u)) >> 16;
}
__device__ __forceinline__ u32 pk(float a, float b) {
    return f2bf(a) | (f2bf(b) << 16);
}
__device__ __forceinline__ u32 f2bf_fast(float f) {  // round-half-up, 2 inst
    return (__float_as_uint(f) + 0x8000u) >> 16;
}
__device__ __forceinline__ u32 pk_fast(float a, float b) {
    return f2bf_fast(a) | (f2bf_fast(b) << 16);
}
__device__ __forceinline__ float bflo(u32 u) { return __uint_as_float(u << 16); }
__device__ __forceinline__ float bfhi(u32 u) { return __uint_as_float(u & 0xffff0000u); }
__device__ __forceinline__ float bfu(u16 u) { return __uint_as_float(((u32)u) << 16); }

union U8 { u32 u[4]; short8 v; };

// ---------- input projection + LayerNorm + ReLU (wave per node), bf16 state ----------
__global__ void k_input_proj(const float* __restrict__ x, const float* __restrict__ in_w,
                             const float* __restrict__ in_b, const float* __restrict__ ln_g,
                             const float* __restrict__ ln_b, u16* __restrict__ hbf, int n_nodes) {
    const int lane = threadIdx.x & 63;
    const int node = blockIdx.x * 4 + (threadIdx.x >> 6);
    if (node >= n_nodes) return;
    float acc = in_b[lane];
#pragma unroll
    for (int k = 0; k < 4; ++k) acc = fmaf(x[node * 4 + k], in_w[k * 64 + lane], acc);
    float s = acc;
#pragma unroll
    for (int off = 32; off > 0; off >>= 1) s += __shfl_xor(s, off);
    float mu = s * (1.f / 64.f);
    float d = acc - mu;
    float vs = d * d;
#pragma unroll
    for (int off = 32; off > 0; off >>= 1) vs += __shfl_xor(vs, off);
    float inv = rsqrtf(vs * (1.f / 64.f) + 1e-5f);
    float hv = fmaxf(d * inv * ln_g[lane] + ln_b[lane], 0.f);
    hbf[(size_t)node * 64 + lane] = (u16)f2bf(hv);
}

// ---------- (type,dst)-sort: histogram, scan, dst-fill, scatter ----------
__global__ void k_hist(const int* __restrict__ dst, const int* __restrict__ ety,
                       int* __restrict__ cnt, int M, int N) {
    int i = blockIdx.x * 256 + threadIdx.x;
    if (i < M) atomicAdd(&cnt[(ety[i] & 1) * N + dst[i]], 1);
}

__global__ void k_scan1(int* __restrict__ data, int* __restrict__ part, int N) {
    __shared__ int s[1024];
    const int t = threadIdx.x;
    const int i = blockIdx.x * 1024 + t;
    int v = (i < N) ? data[i] : 0;
    s[t] = v;
    __syncthreads();
#pragma unroll
    for (int d = 1; d < 1024; d <<= 1) {
        int x = (t >= d) ? s[t - d] : 0;
        __syncthreads();
        s[t] += x;
        __syncthreads();
    }
    if (i < N) data[i] = s[t] - v;  // exclusive
    if (t == 1023) part[blockIdx.x] = s[1023];
}

__global__ void k_scan2(int* __restrict__ part, int nb) {
    if (threadIdx.x == 0 && blockIdx.x == 0) {
        int a = 0;
        for (int i = 0; i < nb; ++i) { int t = part[i]; part[i] = a; a += t; }
    }
}

__global__ void k_scan3(int* __restrict__ data, const int* __restrict__ part, int N,
                        int saveIdx, int* __restrict__ slot) {
    int i = blockIdx.x * 1024 + threadIdx.x;
    if (i < N) {
        int v = data[i] + part[blockIdx.x];
        data[i] = v;
        if (i == saveIdx) slot[0] = v;  // T0 = # of type-0 edges
    }
}

// sequential dst fill from CSR bins (replaces scattered dstP writes)
__global__ void k_filldst(const int* __restrict__ off, int* __restrict__ dstP,
                          int NB, int N, int M) {
    int b = blockIdx.x * 256 + threadIdx.x;
    if (b >= NB) return;
    int s = off[b];
    int e = (b + 1 < NB) ? off[b + 1] : M;
    int d = (b >= N) ? b - N : b;
    for (int p = s; p < e; ++p) dstP[p] = d;
}

__global__ void k_scatter(const int* __restrict__ src, const int* __restrict__ dst,
                          const int* __restrict__ ety, int* __restrict__ cursor,
                          int* __restrict__ srcP, int M, int N) {
    int e = blockIdx.x * 256 + threadIdx.x;
    if (e < M) {
        int d = dst[e];
        int t = ety[e] & 1;
        int pos = atomicAdd(&cursor[t * N + d], 1);
        srcP[pos] = src[e] & 0x3FFFFFFF;
    }
}

// ---------- edge message MLP: one tile per wave, zero barriers, 1-deep pipeline ----------
__global__ __launch_bounds__(256, 2) void k_edge_mlp(
    const u16* __restrict__ hbf, const int* __restrict__ srcP, const int* __restrict__ dstP,
    const int* __restrict__ t0p, const float* __restrict__ w1, const float* __restrict__ b1,
    const float* __restrict__ w2, const float* __restrict__ b2,
    float* __restrict__ agg, int M) {
    __shared__ u16 sHid[4][4608];   // per-wave hidden [row][col] stride 72
    __shared__ u16 sMsg[4][4864];   // per-wave msg    [col][edge] stride 76 (disjoint)

    const int tid = threadIdx.x;
    const int l = tid & 63, wv = tid >> 6;
    const int l15 = l & 15, quad = l >> 4;
    const f32x4 vz = {0.f, 0.f, 0.f, 0.f};

    const int T0 = *t0p;
    const int half = gridDim.x >> 1;
    const int ty = (blockIdx.x >= half) ? 1 : 0;
    const int bi = ty ? (int)blockIdx.x - half : (int)blockIdx.x;

    const int n_tiles = (M + 63) >> 6;
    const int tlo = ty ? (T0 >> 6) : 0;
    const int thi = ty ? n_tiles : ((T0 + 63) >> 6);
    const int lo = ty ? T0 : 0;
    const int hi = ty ? M : T0;
    const int range = thi - tlo;
    const int per = (range + half - 1) / half;
    const int c0 = tlo + bi * per;
    const int c1 = min(c0 + per, thi);

    // ---- register B fragments + biases for this block's type (static idx) ----
    short8 Bf1[4][4], Bf2[2][4];
    float b1r[4], b2r[4];
#pragma unroll
    for (int ni = 0; ni < 4; ++ni) {
        const int c = ni * 16 + l15;
        b1r[ni] = b1[ty * 64 + c];
        b2r[ni] = b2[ty * 64 + c];
#pragma unroll
        for (int s = 0; s < 4; ++s) {
            U8 tmp;
            const float* wp = w1 + (size_t)ty * 8192 + (size_t)(s * 32 + quad * 8) * 64 + c;
#pragma unroll
            for (int jp = 0; jp < 4; ++jp) tmp.u[jp] = pk(wp[(2 * jp) * 64], wp[(2 * jp + 1) * 64]);
            Bf1[s][ni] = tmp.v;
        }
#pragma unroll
        for (int s = 0; s < 2; ++s) {
            U8 tmp;
            const float* wp = w2 + (size_t)ty * 4096 + (size_t)(s * 32 + quad * 8) * 64 + c;
#pragma unroll
            for (int jp = 0; jp < 4; ++jp) tmp.u[jp] = pk(wp[(2 * jp) * 64], wp[(2 * jp + 1) * 64]);
            Bf2[s][ni] = tmp.v;
        }
    }

    u16* hid = sHid[wv];
    u16* msg = sMsg[wv];

    int t = c0 + wv;
    int mdr_c = -1;
    int rs[4], rd[4];
    short8 a1[4][4];
    if (t < c1) {  // prologue
        int ec = min((t << 6) + l, M - 1);
        int ms = srcP[ec];
        mdr_c = dstP[ec];
#pragma unroll
        for (int mi = 0; mi < 4; ++mi) {
            rs[mi] = __shfl(ms, mi * 16 + l15);
            rd[mi] = __shfl(mdr_c, mi * 16 + l15);
        }
#pragma unroll
        for (int mi = 0; mi < 4; ++mi)
#pragma unroll
            for (int s = 0; s < 4; ++s) {
                const int row = (s < 2) ? rs[mi] : rd[mi];
                a1[mi][s] = *(const short8*)(hbf + (size_t)row * 64 + (s & 1) * 32 + quad * 8);
            }
    }

    for (; t < c1; t += 4) {
        const int base = t << 6;
        const int ecn = min(((t + 4) << 6) + l, M - 1);
        int msr_n = srcP[ecn];
        int mdr_n = dstP[ecn];

        // ---- layer 1 ----
#pragma unroll
        for (int mi = 0; mi < 4; ++mi) {
            f32x4 acc[4] = {vz, vz, vz, vz};
#pragma unroll
            for (int s = 0; s < 4; ++s)
#pragma unroll
                for (int ni = 0; ni < 4; ++ni)
                    acc[ni] = __builtin_amdgcn_mfma_f32_16x16x32_bf16(a1[mi][s], Bf1[s][ni], acc[ni], 0, 0, 0);
#pragma unroll
            for (int ni = 0; ni < 4; ++ni) {
                const int c = ni * 16 + l15;
#pragma unroll
                for (int r = 0; r < 4; ++r) {
                    float hv = fmaxf(acc[ni][r] + b1r[ni], 0.f);
                    hid[(mi * 16 + quad * 4 + r) * 72 + c] = (u16)f2bf_fast(hv);
                }
            }
        }

        // ---- next tile's A-gathers ----
#pragma unroll
        for (int mi = 0; mi < 4; ++mi) {
            rs[mi] = __shfl(msr_n, mi * 16 + l15);
            rd[mi] = __shfl(mdr_n, mi * 16 + l15);
        }
#pragma unroll
        for (int mi = 0; mi < 4; ++mi)
#pragma unroll
            for (int s = 0; s < 4; ++s) {
                const int row = (s < 2) ? rs[mi] : rd[mi];
                a1[mi][s] = *(const short8*)(hbf + (size_t)row * 64 + (s & 1) * 32 + quad * 8);
            }

        // ---- layer 2 ----
#pragma unroll
        for (int mi = 0; mi < 4; ++mi) {
            short8 a2a = *(const short8*)(hid + (mi * 16 + l15) * 72 + quad * 8);
            short8 a2b = *(const short8*)(hid + (mi * 16 + l15) * 72 + 32 + quad * 8);
#pragma unroll
            for (int ni = 0; ni < 4; ++ni) {
                f32x4 tt = __builtin_amdgcn_mfma_f32_16x16x32_bf16(a2a, Bf2[0][ni], vz, 0, 0, 0);
                f32x4 m2 = __builtin_amdgcn_mfma_f32_16x16x32_bf16(a2b, Bf2[1][ni], tt, 0, 0, 0);
                const int c = ni * 16 + l15;
                const int e0 = mi * 16 + quad * 4;
                const float bb = b2r[ni];
                *(u32*)(msg + c * 76 + e0) = pk_fast(m2[0] + bb, m2[1] + bb);
                *(u32*)(msg + c * 76 + e0 + 2) = pk_fast(m2[2] + bb, m2[3] + bb);
            }
        }

        // ---- run-reduction: ballot mask in SGPRs, scalar branch per run-end ----
        {
            int eg = base + l;
            int dvz = (eg >= lo && eg < hi) ? mdr_c : -1;
            int dprev = __shfl_up(dvz, 1);
            u64 mask = __ballot((l == 0) || (dvz != dprev));
            float a = 0.f;
#pragma unroll
            for (int i = 0; i < 64; i += 4) {
                uint2 pr = *(const uint2*)(msg + l * 76 + i);
                float v0 = bflo(pr.x), v1 = bfhi(pr.x), v2 = bflo(pr.y), v3 = bfhi(pr.y);
#define RR_STEP(ii, vv)                                                         \
                a += (vv);                                                      \
                if ((ii) == 63 || ((mask >> ((ii) + 1)) & 1ull)) {              \
                    int dd = __builtin_amdgcn_readlane(dvz, (ii));              \
                    if (dd >= 0) unsafeAtomicAdd(agg + (size_t)dd * 64 + l, a); \
                    a = 0.f;                                                    \
                }
                RR_STEP(i, v0)
                RR_STEP(i + 1, v1)
                RR_STEP(i + 2, v2)
                RR_STEP(i + 3, v3)
#undef RR_STEP
            }
        }
        mdr_c = mdr_n;
    }
}

// ---------- GRU via MFMA (bf16 state): one 16-node tile per wave; fused combine + agg re-zero ----------
__global__ __launch_bounds__(256, 3) void k_gru_gemm(
    float* __restrict__ agg, u16* __restrict__ hbf,
    const float* __restrict__ wi, const float* __restrict__ wh,
    const float* __restrict__ bi, const float* __restrict__ bh, int n_nodes) {
    extern __shared__ u16 smem[];
    u16* sRZ = smem;                 // 128 cols x stride 136 (r|z), K=128=[agg|h]
    u16* sIN = smem + 128 * 136;     // 64 cols x stride 72, K=64 (agg)
    u16* sHN = sIN + 64 * 72;        // 64 cols x stride 72, K=64 (h)

    const int tid = threadIdx.x;
    const int l = tid & 63, wv = tid >> 6;
    const int l15 = l & 15, quad = l >> 4;
    const f32x4 vz = {0.f, 0.f, 0.f, 0.f};

    for (int u = tid; u < 128 * 64; u += 256) {
        int c = u >> 6, k0 = (u & 63) * 2;
        float v0 = (k0 < 64) ? wi[k0 * 192 + c] : wh[(k0 - 64) * 192 + c];
        float v1 = (k0 < 64) ? wi[(k0 + 1) * 192 + c] : wh[(k0 + 1 - 64) * 192 + c];
        *(u32*)(sRZ + c * 136 + k0) = pk(v0, v1);
    }
    for (int u = tid; u < 64 * 32; u += 256) {
        int c = u >> 5, k0 = (u & 31) * 2;
        *(u32*)(sIN + c * 72 + k0) = pk(wi[k0 * 192 + 128 + c], wi[(k0 + 1) * 192 + 128 + c]);
        *(u32*)(sHN + c * 72 + k0) = pk(wh[k0 * 192 + 128 + c], wh[(k0 + 1) * 192 + 128 + c]);
    }
    float bR[4], bZ[4], bI[4], bH[4];
#pragma unroll
    for (int nt = 0; nt < 4; ++nt) {
        int j = nt * 16 + l15;
        bR[nt] = bi[j] + bh[j];
        bZ[nt] = bi[64 + j] + bh[64 + j];
        bI[nt] = bi[128 + j];
        bH[nt] = bh[128 + j];
    }
    __syncthreads();  // the only barrier

    const f32x4 z4 = {0.f, 0.f, 0.f, 0.f};
    const int n_tiles = (n_nodes + 15) >> 4;
    for (int tile = blockIdx.x * 4 + wv; tile < n_tiles; tile += gridDim.x * 4) {
        const int nb = tile << 4;
        const int arow = nb + l15;
        const int rowc = (arow < n_nodes) ? arow : (n_nodes - 1);
        short8 aA[2], aH[2];
#pragma unroll
        for (int s = 0; s < 2; ++s) {
            const float* ap = agg + (size_t)rowc * 64 + s * 32 + quad * 8;
            U8 tt;
#pragma unroll
            for (int jp = 0; jp < 4; ++jp) tt.u[jp] = pk(ap[2 * jp], ap[2 * jp + 1]);
            aA[s] = tt.v;
            aH[s] = *(const short8*)(hbf + (size_t)rowc * 64 + s * 32 + quad * 8);
        }
        // re-zero agg for the next layer (this tile's rows are exclusively ours)
        if (arow < n_nodes) {
#pragma unroll
            for (int s = 0; s < 2; ++s) {
                *(f32x4*)(agg + (size_t)rowc * 64 + s * 32 + quad * 8) = z4;
                *(f32x4*)(agg + (size_t)rowc * 64 + s * 32 + quad * 8 + 4) = z4;
            }
        }
        f32x4 D[16];
#pragma unroll
        for (int i = 0; i < 16; ++i) D[i] = vz;
#pragma unroll
        for (int nt = 0; nt < 8; ++nt) {
            const u16* bp = sRZ + (nt * 16 + l15) * 136 + quad * 8;
            D[nt] = __builtin_amdgcn_mfma_f32_16x16x32_bf16(aA[0], *(const short8*)bp, D[nt], 0, 0, 0);
            D[nt] = __builtin_amdgcn_mfma_f32_16x16x32_bf16(aA[1], *(const short8*)(bp + 32), D[nt], 0, 0, 0);
            D[nt] = __builtin_amdgcn_mfma_f32_16x16x32_bf16(aH[0], *(const short8*)(bp + 64), D[nt], 0, 0, 0);
            D[nt] = __builtin_amdgcn_mfma_f32_16x16x32_bf16(aH[1], *(const short8*)(bp + 96), D[nt], 0, 0, 0);
        }
#pragma unroll
        for (int nt = 0; nt < 4; ++nt) {
            const u16* ip = sIN + (nt * 16 + l15) * 72 + quad * 8;
            D[8 + nt] = __builtin_amdgcn_mfma_f32_16x16x32_bf16(aA[0], *(const short8*)ip, D[8 + nt], 0, 0, 0);
            D[8 + nt] = __builtin_amdgcn_mfma_f32_16x16x32_bf16(aA[1], *(const short8*)(ip + 32), D[8 + nt], 0, 0, 0);
            const u16* hp = sHN + (nt * 16 + l15) * 72 + quad * 8;
            D[12 + nt] = __builtin_amdgcn_mfma_f32_16x16x32_bf16(aH[0], *(const short8*)hp, D[12 + nt], 0, 0, 0);
            D[12 + nt] = __builtin_amdgcn_mfma_f32_16x16x32_bf16(aH[1], *(const short8*)(hp + 32), D[12 + nt], 0, 0, 0);
        }
#pragma unroll
        for (int nt = 0; nt < 4; ++nt) {
            const int j = nt * 16 + l15;
#pragma unroll
            for (int r = 0; r < 4; ++r) {
                const int nd = nb + quad * 4 + r;
                if (nd < n_nodes) {
                    float rsv = D[nt][r] + bR[nt];
                    float zsv = D[4 + nt][r] + bZ[nt];
                    float inv = D[8 + nt][r] + bI[nt];
                    float hnv = D[12 + nt][r] + bH[nt];
                    float rr = 1.f / (1.f + __expf(-rsv));
                    float zz = 1.f / (1.f + __expf(-zsv));
                    float nn = tanhf(fmaf(rr, hnv, inv));
                    float hv = bfu(hbf[(size_t)nd * 64 + j]);  // bf16 recurrent state
                    float nh = (1.f - zz) * nn + zz * hv;
                    hbf[(size_t)nd * 64 + j] = (u16)f2bf(nh);
                }
            }
        }
    }
}

// ---------- readout + data-qubit correction (wave per node, bf16 h) ----------
__global__ void k_readout(const u16* __restrict__ hbf, const float* __restrict__ x,
                          const int* __restrict__ node_type, const float* __restrict__ w1,
                          const float* __restrict__ b1, const float* __restrict__ w2,
                          const float* __restrict__ b2, float* __restrict__ out, int n_nodes) {
    const int lane = threadIdx.x & 63;
    const int node = blockIdx.x * 4 + (threadIdx.x >> 6);
    if (node >= n_nodes) return;
    float hv = bfu(hbf[(size_t)node * 64 + lane]);
    float acc = b1[lane];
    for (int k = 0; k < 64; ++k) acc = fmaf(__shfl(hv, k), w1[k * 64 + lane], acc);
    float t = fmaxf(acc, 0.f) * w2[lane];
#pragma unroll
    for (int off = 32; off > 0; off >>= 1) t += __shfl_xor(t, off);
    if (lane == 0) {
        float o = t + b2[0];
        out[node] = (node_type[node] == 0) ? (x[node * 4] + o) : 0.f;
    }
}

extern "C" void kernel_launch(void* const* d_in, const int* in_sizes, int n_in, void* d_out,
                              int out_size, void* d_ws, size_t ws_size, hipStream_t stream) {
    const float* x = (const float*)d_in[0];
    const int* node_type = (const int*)d_in[1];
    const int* edge_index = (const int*)d_in[2];
    const int* edge_type = (const int*)d_in[3];
    const float* in_w = (const float*)d_in[4];
    const float* in_b = (const float*)d_in[5];
    const float* ln_g = (const float*)d_in[6];
    const float* ln_b = (const float*)d_in[7];
    const float* mlp_w1 = (const float*)d_in[8];
    const float* mlp_b1 = (const float*)d_in[9];
    const float* mlp_w2 = (const float*)d_in[10];
    const float* mlp_b2 = (const float*)d_in[11];
    const float* gru_wi = (const float*)d_in[12];
    const float* gru_wh = (const float*)d_in[13];
    const float* gru_bi = (const float*)d_in[14];
    const float* gru_bh = (const float*)d_in[15];
    const float* ro_w1 = (const float*)d_in[16];
    const float* ro_b1 = (const float*)d_in[17];
    const float* ro_w2 = (const float*)d_in[18];
    const float* ro_b2 = (const float*)d_in[19];

    const int N = in_sizes[1];  // nodes
    const int M = in_sizes[3];  // edges
    const int* src = edge_index;
    const int* dst = edge_index + M;

    // ws: agg (N*256B) | hbf (N*128B) | off (2N*4) | part (4KB) | srcP (M*4) | dstP (M*4)
    char* wsb = (char*)d_ws;
    float* agg = (float*)wsb;
    u16* hbf = (u16*)(wsb + (size_t)N * 256);
    int* off = (int*)(wsb + (size_t)N * 384);
    int* part = (int*)(wsb + (size_t)N * 384 + (size_t)2 * N * 4);
    int* srcP = (int*)(wsb + (size_t)N * 384 + (size_t)2 * N * 4 + 4096);
    int* dstP = srcP + M;
    int* t0slot = part + 1000;

    const int NB = 2 * N;
    const int nb = (NB + 1023) / 1024;

    // build (type,dst)-sorted edge permutation (reused by all 3 layers)
    hipMemsetAsync(off, 0, (size_t)NB * sizeof(int), stream);
    k_hist<<<(M + 255) / 256, 256, 0, stream>>>(dst, edge_type, off, M, N);
    k_scan1<<<nb, 1024, 0, stream>>>(off, part, NB);
    k_scan2<<<1, 64, 0, stream>>>(part, nb);
    k_scan3<<<nb, 1024, 0, stream>>>(off, part, NB, N, t0slot);
    k_filldst<<<(NB + 255) / 256, 256, 0, stream>>>(off, dstP, NB, N, M);  // before cursors mutate
    k_scatter<<<(M + 255) / 256, 256, 0, stream>>>(src, dst, edge_type, off, srcP, M, N);

    k_input_proj<<<(N + 3) / 4, 256, 0, stream>>>(x, in_w, in_b, ln_g, ln_b, hbf, N);
    hipMemsetAsync(agg, 0, (size_t)N * 64 * sizeof(float), stream);  // layer 0 only; GRU re-zeros
    const size_t gruLds = (size_t)(128 * 136 + 64 * 72 + 64 * 72) * sizeof(u16);  // 53248
    for (int l = 0; l < 3; ++l) {
        k_edge_mlp<<<1024, 256, 0, stream>>>(hbf, srcP, dstP, t0slot,
                                             mlp_w1 + (size_t)l * 2 * 128 * 64,
                                             mlp_b1 + (size_t)l * 2 * 64,
                                             mlp_w2 + (size_t)l * 2 * 64 * 64,
                                             mlp_b2 + (size_t)l * 2 * 64, agg, M);
        k_gru_gemm<<<512, 256, gruLds, stream>>>(agg, hbf, gru_wi + (size_t)l * 64 * 192,
                                                 gru_wh + (size_t)l * 64 * 192,
                                                 gru_bi + (size_t)l * 192, gru_bh + (size_t)l * 192, N);
    }
    k_readout<<<(N + 3) / 4, 256, 0, stream>>>(hbf, x, node_type, ro_w1, ro_b1, ro_w2, ro_b2,
                                               (float*)d_out, N);
}

// Round 8
// 1009.250 us; speedup vs baseline: 7.3766x; 1.0693x over previous
//
#include <hip/hip_runtime.h>

typedef unsigned int u32;
typedef unsigned short u16;
typedef unsigned long long u64;

using short8 = __attribute__((ext_vector_type(8))) short;
using f32x4  = __attribute__((ext_vector_type(4))) float;

// ---------- bf16 helpers ----------
__device__ __forceinline__ u32 f2bf(float f) {  // RTN-even (weights/A staging)
    u32 u = __float_as_uint(f);
    return (u + 0x7fffu + ((u >> 16) & 1u)) >> 16;
}
__device__ __forceinline__ u32 pk(float a, float b) {
    return f2bf(a) | (f2bf(b) << 16);
}
__device__ __forceinline__ u32 f2bf_fast(float f) {  // round-half-up, 2 inst
    return (__float_as_uint(f) + 0x8000u) >> 16;
}
__device__ __forceinline__ u32 pk_fast(float a, float b) {
    return f2bf_fast(a) | (f2bf_fast(b) << 16);
}
__device__ __forceinline__ float bflo(u32 u) { return __uint_as_float(u << 16); }
__device__ __forceinline__ float bfhi(u32 u) { return __uint_as_float(u & 0xffff0000u); }
__device__ __forceinline__ float bfu(u16 u) { return __uint_as_float(((u32)u) << 16); }

union U8 { u32 u[4]; short8 v; };

// ---------- input projection + LayerNorm + ReLU (wave per node), bf16 state ----------
__global__ void k_input_proj(const float* __restrict__ x, const float* __restrict__ in_w,
                             const float* __restrict__ in_b, const float* __restrict__ ln_g,
                             const float* __restrict__ ln_b, u16* __restrict__ hbf, int n_nodes) {
    const int lane = threadIdx.x & 63;
    const int node = blockIdx.x * 4 + (threadIdx.x >> 6);
    if (node >= n_nodes) return;
    float acc = in_b[lane];
#pragma unroll
    for (int k = 0; k < 4; ++k) acc = fmaf(x[node * 4 + k], in_w[k * 64 + lane], acc);
    float s = acc;
#pragma unroll
    for (int off = 32; off > 0; off >>= 1) s += __shfl_xor(s, off);
    float mu = s * (1.f / 64.f);
    float d = acc - mu;
    float vs = d * d;
#pragma unroll
    for (int off = 32; off > 0; off >>= 1) vs += __shfl_xor(vs, off);
    float inv = rsqrtf(vs * (1.f / 64.f) + 1e-5f);
    float hv = fmaxf(d * inv * ln_g[lane] + ln_b[lane], 0.f);
    hbf[(size_t)node * 64 + lane] = (u16)f2bf(hv);
}

// ---------- (type,dst)-sort: histogram, scan, dst-fill, partitioned scatter ----------
__global__ void k_hist(const int* __restrict__ dst, const int* __restrict__ ety,
                       int* __restrict__ cnt, int M, int N) {
    int i = blockIdx.x * 256 + threadIdx.x;
    if (i < M) atomicAdd(&cnt[(ety[i] & 1) * N + dst[i]], 1);
}

__global__ void k_scan1(int* __restrict__ data, int* __restrict__ part, int N) {
    __shared__ int s[1024];
    const int t = threadIdx.x;
    const int i = blockIdx.x * 1024 + t;
    int v = (i < N) ? data[i] : 0;
    s[t] = v;
    __syncthreads();
#pragma unroll
    for (int d = 1; d < 1024; d <<= 1) {
        int x = (t >= d) ? s[t - d] : 0;
        __syncthreads();
        s[t] += x;
        __syncthreads();
    }
    if (i < N) data[i] = s[t] - v;  // exclusive
    if (t == 1023) part[blockIdx.x] = s[1023];
}

// wave-parallel exclusive scan of block partials (replaces serial 1-thread loop)
__global__ void k_scan2(int* __restrict__ part, int nb) {
    const int l = threadIdx.x & 63;
    int base = 0;
    for (int s = 0; s < nb; s += 64) {
        int i = s + l;
        int orig = (i < nb) ? part[i] : 0;
        int x = orig;
#pragma unroll
        for (int off = 1; off < 64; off <<= 1) {
            int t = __shfl_up(x, off);
            if (l >= off) x += t;
        }
        if (i < nb) part[i] = base + x - orig;  // exclusive
        base += __shfl(x, 63);                  // chunk total
    }
}

__global__ void k_scan3(int* __restrict__ data, const int* __restrict__ part, int N,
                        int saveIdx, int* __restrict__ slot) {
    int i = blockIdx.x * 1024 + threadIdx.x;
    if (i < N) {
        int v = data[i] + part[blockIdx.x];
        data[i] = v;
        if (i == saveIdx) slot[0] = v;  // T0 = # of type-0 edges
    }
}

// sequential dst fill from CSR bins (replaces scattered dstP writes)
__global__ void k_filldst(const int* __restrict__ off, int* __restrict__ dstP,
                          int NB, int N, int M) {
    int b = blockIdx.x * 256 + threadIdx.x;
    if (b >= NB) return;
    int s = off[b];
    int e = (b + 1 < NB) ? off[b + 1] : M;
    int d = (b >= N) ? b - N : b;
    for (int p = s; p < e; ++p) dstP[p] = d;
}

// XCD-partitioned scatter: group g (blockIdx&7, the usual block->XCD round-robin)
// commits only edges whose dst partition == g, so all writes to a srcP line come
// from one XCD and its L2 assembles full lines (perf heuristic; correctness holds
// for any block->XCD mapping since the partition function is pure in d).
__global__ void k_scatter(const int* __restrict__ src, const int* __restrict__ dst,
                          const int* __restrict__ ety, int* __restrict__ cursor,
                          int* __restrict__ srcP, int M, int N, int nd8) {
    const int g = blockIdx.x & 7;
    const int nb = gridDim.x >> 3;
    const int bi = blockIdx.x >> 3;
    for (int e = bi * 256 + threadIdx.x; e < M; e += nb * 256) {
        int d = dst[e];
        if (d / nd8 == g) {
            int t = ety[e] & 1;
            int pos = atomicAdd(&cursor[t * N + d], 1);
            srcP[pos] = src[e] & 0x3FFFFFFF;
        }
    }
}

// ---------- edge message MLP: one tile per wave, zero barriers, 1-deep pipeline ----------
__global__ __launch_bounds__(256, 2) void k_edge_mlp(
    const u16* __restrict__ hbf, const int* __restrict__ srcP, const int* __restrict__ dstP,
    const int* __restrict__ t0p, const float* __restrict__ w1, const float* __restrict__ b1,
    const float* __restrict__ w2, const float* __restrict__ b2,
    float* __restrict__ agg, int M) {
    __shared__ u16 sHid[4][4608];   // per-wave hidden [row][col] stride 72
    __shared__ u16 sMsg[4][4864];   // per-wave msg    [col][edge] stride 76 (disjoint)

    const int tid = threadIdx.x;
    const int l = tid & 63, wv = tid >> 6;
    const int l15 = l & 15, quad = l >> 4;
    const f32x4 vz = {0.f, 0.f, 0.f, 0.f};

    const int T0 = *t0p;
    const int half = gridDim.x >> 1;
    const int ty = (blockIdx.x >= half) ? 1 : 0;
    const int bi = ty ? (int)blockIdx.x - half : (int)blockIdx.x;

    const int n_tiles = (M + 63) >> 6;
    const int tlo = ty ? (T0 >> 6) : 0;
    const int thi = ty ? n_tiles : ((T0 + 63) >> 6);
    const int lo = ty ? T0 : 0;
    const int hi = ty ? M : T0;
    const int range = thi - tlo;
    const int per = (range + half - 1) / half;
    const int c0 = tlo + bi * per;
    const int c1 = min(c0 + per, thi);

    // ---- register B fragments + biases for this block's type (static idx) ----
    short8 Bf1[4][4], Bf2[2][4];
    float b1r[4], b2r[4];
#pragma unroll
    for (int ni = 0; ni < 4; ++ni) {
        const int c = ni * 16 + l15;
        b1r[ni] = b1[ty * 64 + c];
        b2r[ni] = b2[ty * 64 + c];
#pragma unroll
        for (int s = 0; s < 4; ++s) {
            U8 tmp;
            const float* wp = w1 + (size_t)ty * 8192 + (size_t)(s * 32 + quad * 8) * 64 + c;
#pragma unroll
            for (int jp = 0; jp < 4; ++jp) tmp.u[jp] = pk(wp[(2 * jp) * 64], wp[(2 * jp + 1) * 64]);
            Bf1[s][ni] = tmp.v;
        }
#pragma unroll
        for (int s = 0; s < 2; ++s) {
            U8 tmp;
            const float* wp = w2 + (size_t)ty * 4096 + (size_t)(s * 32 + quad * 8) * 64 + c;
#pragma unroll
            for (int jp = 0; jp < 4; ++jp) tmp.u[jp] = pk(wp[(2 * jp) * 64], wp[(2 * jp + 1) * 64]);
            Bf2[s][ni] = tmp.v;
        }
    }

    u16* hid = sHid[wv];
    u16* msg = sMsg[wv];

    int t = c0 + wv;
    int mdr_c = -1;
    int rs[4], rd[4];
    short8 a1[4][4];
    if (t < c1) {  // prologue
        int ec = min((t << 6) + l, M - 1);
        int ms = srcP[ec];
        mdr_c = dstP[ec];
#pragma unroll
        for (int mi = 0; mi < 4; ++mi) {
            rs[mi] = __shfl(ms, mi * 16 + l15);
            rd[mi] = __shfl(mdr_c, mi * 16 + l15);
        }
#pragma unroll
        for (int mi = 0; mi < 4; ++mi)
#pragma unroll
            for (int s = 0; s < 4; ++s) {
                const int row = (s < 2) ? rs[mi] : rd[mi];
                a1[mi][s] = *(const short8*)(hbf + (size_t)row * 64 + (s & 1) * 32 + quad * 8);
            }
    }

    for (; t < c1; t += 4) {
        const int base = t << 6;
        const int ecn = min(((t + 4) << 6) + l, M - 1);
        int msr_n = srcP[ecn];
        int mdr_n = dstP[ecn];

        // ---- layer 1 ----
#pragma unroll
        for (int mi = 0; mi < 4; ++mi) {
            f32x4 acc[4] = {vz, vz, vz, vz};
#pragma unroll
            for (int s = 0; s < 4; ++s)
#pragma unroll
                for (int ni = 0; ni < 4; ++ni)
                    acc[ni] = __builtin_amdgcn_mfma_f32_16x16x32_bf16(a1[mi][s], Bf1[s][ni], acc[ni], 0, 0, 0);
#pragma unroll
            for (int ni = 0; ni < 4; ++ni) {
                const int c = ni * 16 + l15;
#pragma unroll
                for (int r = 0; r < 4; ++r) {
                    float hv = fmaxf(acc[ni][r] + b1r[ni], 0.f);
                    hid[(mi * 16 + quad * 4 + r) * 72 + c] = (u16)f2bf_fast(hv);
                }
            }
        }

        // ---- next tile's A-gathers ----
#pragma unroll
        for (int mi = 0; mi < 4; ++mi) {
            rs[mi] = __shfl(msr_n, mi * 16 + l15);
            rd[mi] = __shfl(mdr_n, mi * 16 + l15);
        }
#pragma unroll
        for (int mi = 0; mi < 4; ++mi)
#pragma unroll
            for (int s = 0; s < 4; ++s) {
                const int row = (s < 2) ? rs[mi] : rd[mi];
                a1[mi][s] = *(const short8*)(hbf + (size_t)row * 64 + (s & 1) * 32 + quad * 8);
            }

        // ---- layer 2 ----
#pragma unroll
        for (int mi = 0; mi < 4; ++mi) {
            short8 a2a = *(const short8*)(hid + (mi * 16 + l15) * 72 + quad * 8);
            short8 a2b = *(const short8*)(hid + (mi * 16 + l15) * 72 + 32 + quad * 8);
#pragma unroll
            for (int ni = 0; ni < 4; ++ni) {
                f32x4 tt = __builtin_amdgcn_mfma_f32_16x16x32_bf16(a2a, Bf2[0][ni], vz, 0, 0, 0);
                f32x4 m2 = __builtin_amdgcn_mfma_f32_16x16x32_bf16(a2b, Bf2[1][ni], tt, 0, 0, 0);
                const int c = ni * 16 + l15;
                const int e0 = mi * 16 + quad * 4;
                const float bb = b2r[ni];
                *(u32*)(msg + c * 76 + e0) = pk_fast(m2[0] + bb, m2[1] + bb);
                *(u32*)(msg + c * 76 + e0 + 2) = pk_fast(m2[2] + bb, m2[3] + bb);
            }
        }

        // ---- run-reduction: ballot mask in SGPRs, scalar branch per run-end ----
        {
            int eg = base + l;
            int dvz = (eg >= lo && eg < hi) ? mdr_c : -1;
            int dprev = __shfl_up(dvz, 1);
            u64 mask = __ballot((l == 0) || (dvz != dprev));
            float a = 0.f;
#pragma unroll
            for (int i = 0; i < 64; i += 4) {
                uint2 pr = *(const uint2*)(msg + l * 76 + i);
                float v0 = bflo(pr.x), v1 = bfhi(pr.x), v2 = bflo(pr.y), v3 = bfhi(pr.y);
#define RR_STEP(ii, vv)                                                         \
                a += (vv);                                                      \
                if ((ii) == 63 || ((mask >> ((ii) + 1)) & 1ull)) {              \
                    int dd = __builtin_amdgcn_readlane(dvz, (ii));              \
                    if (dd >= 0) unsafeAtomicAdd(agg + (size_t)dd * 64 + l, a); \
                    a = 0.f;                                                    \
                }
                RR_STEP(i, v0)
                RR_STEP(i + 1, v1)
                RR_STEP(i + 2, v2)
                RR_STEP(i + 3, v3)
#undef RR_STEP
            }
        }
        mdr_c = mdr_n;
    }
}

// ---------- GRU via MFMA (bf16 state): one 16-node tile per wave; fused combine + agg re-zero ----------
__global__ __launch_bounds__(256, 3) void k_gru_gemm(
    float* __restrict__ agg, u16* __restrict__ hbf,
    const float* __restrict__ wi, const float* __restrict__ wh,
    const float* __restrict__ bi, const float* __restrict__ bh, int n_nodes) {
    extern __shared__ u16 smem[];
    u16* sRZ = smem;                 // 128 cols x stride 136 (r|z), K=128=[agg|h]
    u16* sIN = smem + 128 * 136;     // 64 cols x stride 72, K=64 (agg)
    u16* sHN = sIN + 64 * 72;        // 64 cols x stride 72, K=64 (h)

    const int tid = threadIdx.x;
    const int l = tid & 63, wv = tid >> 6;
    const int l15 = l & 15, quad = l >> 4;
    const f32x4 vz = {0.f, 0.f, 0.f, 0.f};

    for (int u = tid; u < 128 * 64; u += 256) {
        int c = u >> 6, k0 = (u & 63) * 2;
        float v0 = (k0 < 64) ? wi[k0 * 192 + c] : wh[(k0 - 64) * 192 + c];
        float v1 = (k0 < 64) ? wi[(k0 + 1) * 192 + c] : wh[(k0 + 1 - 64) * 192 + c];
        *(u32*)(sRZ + c * 136 + k0) = pk(v0, v1);
    }
    for (int u = tid; u < 64 * 32; u += 256) {
        int c = u >> 5, k0 = (u & 31) * 2;
        *(u32*)(sIN + c * 72 + k0) = pk(wi[k0 * 192 + 128 + c], wi[(k0 + 1) * 192 + 128 + c]);
        *(u32*)(sHN + c * 72 + k0) = pk(wh[k0 * 192 + 128 + c], wh[(k0 + 1) * 192 + 128 + c]);
    }
    float bR[4], bZ[4], bI[4], bH[4];
#pragma unroll
    for (int nt = 0; nt < 4; ++nt) {
        int j = nt * 16 + l15;
        bR[nt] = bi[j] + bh[j];
        bZ[nt] = bi[64 + j] + bh[64 + j];
        bI[nt] = bi[128 + j];
        bH[nt] = bh[128 + j];
    }
    __syncthreads();  // the only barrier

    const f32x4 z4 = {0.f, 0.f, 0.f, 0.f};
    const int n_tiles = (n_nodes + 15) >> 4;
    for (int tile = blockIdx.x * 4 + wv; tile < n_tiles; tile += gridDim.x * 4) {
        const int nb = tile << 4;
        const int arow = nb + l15;
        const int rowc = (arow < n_nodes) ? arow : (n_nodes - 1);
        short8 aA[2], aH[2];
#pragma unroll
        for (int s = 0; s < 2; ++s) {
            const float* ap = agg + (size_t)rowc * 64 + s * 32 + quad * 8;
            U8 tt;
#pragma unroll
            for (int jp = 0; jp < 4; ++jp) tt.u[jp] = pk(ap[2 * jp], ap[2 * jp + 1]);
            aA[s] = tt.v;
            aH[s] = *(const short8*)(hbf + (size_t)rowc * 64 + s * 32 + quad * 8);
        }
        // re-zero agg for the next layer (this tile's rows are exclusively ours)
        if (arow < n_nodes) {
#pragma unroll
            for (int s = 0; s < 2; ++s) {
                *(f32x4*)(agg + (size_t)rowc * 64 + s * 32 + quad * 8) = z4;
                *(f32x4*)(agg + (size_t)rowc * 64 + s * 32 + quad * 8 + 4) = z4;
            }
        }
        f32x4 D[16];
#pragma unroll
        for (int i = 0; i < 16; ++i) D[i] = vz;
#pragma unroll
        for (int nt = 0; nt < 8; ++nt) {
            const u16* bp = sRZ + (nt * 16 + l15) * 136 + quad * 8;
            D[nt] = __builtin_amdgcn_mfma_f32_16x16x32_bf16(aA[0], *(const short8*)bp, D[nt], 0, 0, 0);
            D[nt] = __builtin_amdgcn_mfma_f32_16x16x32_bf16(aA[1], *(const short8*)(bp + 32), D[nt], 0, 0, 0);
            D[nt] = __builtin_amdgcn_mfma_f32_16x16x32_bf16(aH[0], *(const short8*)(bp + 64), D[nt], 0, 0, 0);
            D[nt] = __builtin_amdgcn_mfma_f32_16x16x32_bf16(aH[1], *(const short8*)(bp + 96), D[nt], 0, 0, 0);
        }
#pragma unroll
        for (int nt = 0; nt < 4; ++nt) {
            const u16* ip = sIN + (nt * 16 + l15) * 72 + quad * 8;
            D[8 + nt] = __builtin_amdgcn_mfma_f32_16x16x32_bf16(aA[0], *(const short8*)ip, D[8 + nt], 0, 0, 0);
            D[8 + nt] = __builtin_amdgcn_mfma_f32_16x16x32_bf16(aA[1], *(const short8*)(ip + 32), D[8 + nt], 0, 0, 0);
            const u16* hp = sHN + (nt * 16 + l15) * 72 + quad * 8;
            D[12 + nt] = __builtin_amdgcn_mfma_f32_16x16x32_bf16(aH[0], *(const short8*)hp, D[12 + nt], 0, 0, 0);
            D[12 + nt] = __builtin_amdgcn_mfma_f32_16x16x32_bf16(aH[1], *(const short8*)(hp + 32), D[12 + nt], 0, 0, 0);
        }
#pragma unroll
        for (int nt = 0; nt < 4; ++nt) {
            const int j = nt * 16 + l15;
#pragma unroll
            for (int r = 0; r < 4; ++r) {
                const int nd = nb + quad * 4 + r;
                if (nd < n_nodes) {
                    float rsv = D[nt][r] + bR[nt];
                    float zsv = D[4 + nt][r] + bZ[nt];
                    float inv = D[8 + nt][r] + bI[nt];
                    float hnv = D[12 + nt][r] + bH[nt];
                    float rr = 1.f / (1.f + __expf(-rsv));
                    float zz = 1.f / (1.f + __expf(-zsv));
                    float nn = tanhf(fmaf(rr, hnv, inv));
                    float hv = bfu(hbf[(size_t)nd * 64 + j]);  // bf16 recurrent state
                    float nh = (1.f - zz) * nn + zz * hv;
                    hbf[(size_t)nd * 64 + j] = (u16)f2bf(nh);
                }
            }
        }
    }
}

// ---------- readout + data-qubit correction (wave per node, bf16 h) ----------
__global__ void k_readout(const u16* __restrict__ hbf, const float* __restrict__ x,
                          const int* __restrict__ node_type, const float* __restrict__ w1,
                          const float* __restrict__ b1, const float* __restrict__ w2,
                          const float* __restrict__ b2, float* __restrict__ out, int n_nodes) {
    const int lane = threadIdx.x & 63;
    const int node = blockIdx.x * 4 + (threadIdx.x >> 6);
    if (node >= n_nodes) return;
    float hv = bfu(hbf[(size_t)node * 64 + lane]);
    float acc = b1[lane];
    for (int k = 0; k < 64; ++k) acc = fmaf(__shfl(hv, k), w1[k * 64 + lane], acc);
    float t = fmaxf(acc, 0.f) * w2[lane];
#pragma unroll
    for (int off = 32; off > 0; off >>= 1) t += __shfl_xor(t, off);
    if (lane == 0) {
        float o = t + b2[0];
        out[node] = (node_type[node] == 0) ? (x[node * 4] + o) : 0.f;
    }
}

extern "C" void kernel_launch(void* const* d_in, const int* in_sizes, int n_in, void* d_out,
                              int out_size, void* d_ws, size_t ws_size, hipStream_t stream) {
    const float* x = (const float*)d_in[0];
    const int* node_type = (const int*)d_in[1];
    const int* edge_index = (const int*)d_in[2];
    const int* edge_type = (const int*)d_in[3];
    const float* in_w = (const float*)d_in[4];
    const float* in_b = (const float*)d_in[5];
    const float* ln_g = (const float*)d_in[6];
    const float* ln_b = (const float*)d_in[7];
    const float* mlp_w1 = (const float*)d_in[8];
    const float* mlp_b1 = (const float*)d_in[9];
    const float* mlp_w2 = (const float*)d_in[10];
    const float* mlp_b2 = (const float*)d_in[11];
    const float* gru_wi = (const float*)d_in[12];
    const float* gru_wh = (const float*)d_in[13];
    const float* gru_bi = (const float*)d_in[14];
    const float* gru_bh = (const float*)d_in[15];
    const float* ro_w1 = (const float*)d_in[16];
    const float* ro_b1 = (const float*)d_in[17];
    const float* ro_w2 = (const float*)d_in[18];
    const float* ro_b2 = (const float*)d_in[19];

    const int N = in_sizes[1];  // nodes
    const int M = in_sizes[3];  // edges
    const int* src = edge_index;
    const int* dst = edge_index + M;

    // ws: agg (N*256B) | hbf (N*128B) | off (2N*4) | part (4KB) | srcP (M*4) | dstP (M*4)
    char* wsb = (char*)d_ws;
    float* agg = (float*)wsb;
    u16* hbf = (u16*)(wsb + (size_t)N * 256);
    int* off = (int*)(wsb + (size_t)N * 384);
    int* part = (int*)(wsb + (size_t)N * 384 + (size_t)2 * N * 4);
    int* srcP = (int*)(wsb + (size_t)N * 384 + (size_t)2 * N * 4 + 4096);
    int* dstP = srcP + M;
    int* t0slot = part + 1000;

    const int NB = 2 * N;
    const int nb = (NB + 1023) / 1024;
    const int nd8 = (N + 7) / 8;

    // build (type,dst)-sorted edge permutation (reused by all 3 layers)
    hipMemsetAsync(off, 0, (size_t)NB * sizeof(int), stream);
    k_hist<<<(M + 255) / 256, 256, 0, stream>>>(dst, edge_type, off, M, N);
    k_scan1<<<nb, 1024, 0, stream>>>(off, part, NB);
    k_scan2<<<1, 64, 0, stream>>>(part, nb);
    k_scan3<<<nb, 1024, 0, stream>>>(off, part, NB, N, t0slot);
    k_filldst<<<(NB + 255) / 256, 256, 0, stream>>>(off, dstP, NB, N, M);  // before cursors mutate
    k_scatter<<<2048, 256, 0, stream>>>(src, dst, edge_type, off, srcP, M, N, nd8);

    k_input_proj<<<(N + 3) / 4, 256, 0, stream>>>(x, in_w, in_b, ln_g, ln_b, hbf, N);
    hipMemsetAsync(agg, 0, (size_t)N * 64 * sizeof(float), stream);  // layer 0 only; GRU re-zeros
    const size_t gruLds = (size_t)(128 * 136 + 64 * 72 + 64 * 72) * sizeof(u16);  // 53248
    for (int l = 0; l < 3; ++l) {
        k_edge_mlp<<<1024, 256, 0, stream>>>(hbf, srcP, dstP, t0slot,
                                             mlp_w1 + (size_t)l * 2 * 128 * 64,
                                             mlp_b1 + (size_t)l * 2 * 64,
                                             mlp_w2 + (size_t)l * 2 * 64 * 64,
                                             mlp_b2 + (size_t)l * 2 * 64, agg, M);
        k_gru_gemm<<<768, 256, gruLds, stream>>>(agg, hbf, gru_wi + (size_t)l * 64 * 192,
                                                 gru_wh + (size_t)l * 64 * 192,
                                                 gru_bi + (size_t)l * 192, gru_bh + (size_t)l * 192, N);
    }
    k_readout<<<(N + 3) / 4, 256, 0, stream>>>(hbf, x, node_type, ro_w1, ro_b1, ro_w2, ro_b2,
                                               (float*)d_out, N);
}